// Round 8
// baseline (310.856 us; speedup 1.0000x reference)
//
#include <hip/hip_runtime.h>

#define N_NODES 100000
#define N_EDGES 3200000
#define EPS 1e-5f
#define NODE_BLOCKS 391   // ceil(100000/256)
#define NB 782            // buckets of 128 nodes (dst >> 7)
#define BSTRIDE 4608      // fixed bucket region: mean 4096 + 8 sigma
#define NSUB 3            // chunks of 1536 slots per bucket (3*1536 = 4608)
#define S1_EPB 4096       // halved vs R7: LDS 37KB -> 4 blocks/CU (was 2)
#define S1_BLOCKS 782

typedef unsigned int uint;
typedef uint u32x4 __attribute__((ext_vector_type(4)));
typedef _Float16 f16x8 __attribute__((ext_vector_type(8)));
typedef float f32x16 __attribute__((ext_vector_type(16)));

static __device__ __forceinline__ f16x8 as_h8(u32x4 u) { return __builtin_bit_cast(f16x8, u); }
static __device__ __forceinline__ uint pkh(float a, float b) {
    return __builtin_bit_cast(uint, __builtin_amdgcn_cvt_pkrtz(a, b));
}
// v_permlane32_swap_b32: a' = [a.lo32 | b.lo32], b' = [a.hi32 | b.hi32]
// volatile + this exact usage is the R1-R3 verified pattern. Do NOT touch:
// R5/R6 experiments around this instruction failed verification twice.
static __device__ __forceinline__ void swap32(uint& a, uint& b) {
    asm volatile("v_permlane32_swap_b32 %0, %1" : "+v"(a), "+v"(b));
}
// packed f16 relu: max(x, 0) on both halves. rtz-then-relu == relu-then-rtz.
static __device__ __forceinline__ uint prelu(uint u, uint z) {
    uint r;
    asm("v_pk_max_f16 %0, %1, %2" : "=v"(r) : "v"(u), "v"(z));
    return r;
}

#define MFMA(A, B, C) __builtin_amdgcn_mfma_f32_32x32x16_f16(as_h8(A), as_h8(B), (C), 0, 0, 0)

// Repack MFMA C (32 rows x 32 edge-cols, row=(r&3)+8*(r>>2)+4*hi) into the two
// B-fragments for the next K=32 MFMA pair, applying relu in packed f16.
// Verified pattern (passing R1-R3,R7 kernels): pkh pairs + 4x permlane32_swap.
static __device__ __forceinline__ void repack(const f32x16& c, u32x4& f0, u32x4& f1, uint z) {
    uint p0 = prelu(pkh(c[0], c[1]), z),   p1 = prelu(pkh(c[2], c[3]), z);
    uint q0 = prelu(pkh(c[4], c[5]), z),   q1 = prelu(pkh(c[6], c[7]), z);
    uint p2 = prelu(pkh(c[8], c[9]), z),   p3 = prelu(pkh(c[10], c[11]), z);
    uint q2 = prelu(pkh(c[12], c[13]), z), q3 = prelu(pkh(c[14], c[15]), z);
    swap32(p0, q0); swap32(p1, q1);
    swap32(p2, q2); swap32(p3, q3);
    f0.x = p0; f0.y = p1; f0.z = q0; f0.w = q1;
    f1.x = p2; f1.y = p3; f1.z = q2; f1.w = q3;
}

static __device__ __forceinline__ void decode4(const int4& q, int* ss, int* ia) {
    int e0 = q.x, e1 = q.y, e2 = q.z, e3 = q.w;
    ss[0] = e0 & 0x1FFFF; ia[0] = (e0 >> 17) & 127;
    ss[1] = e1 & 0x1FFFF; ia[1] = (e1 >> 17) & 127;
    ss[2] = e2 & 0x1FFFF; ia[2] = (e2 >> 17) & 127;
    ss[3] = e3 & 0x1FFFF; ia[3] = (e3 >> 17) & 127;
    #pragma unroll
    for (int k = 0; k < 4; k++)
        if (ss[k] >= N_NODES) ss[k] = 0;   // slots >= cb hold stale garbage
}

// ---- workspace layout (bytes) ----
#define OFF_STATS  0          // 8 doubles (bn sums)          [zeroed]
#define OFF_BCNT   1024       // int[782] bucket counts       [zeroed]
#define OFF_INVCNT 5120       // float[100000]
#define OFF_AGG1   405120     // float2[100000]
#define OFF_DECW   1205120    // dec MFMA tables: 2112 dwords = 8448B (hole is 9728B)
#define OFF_BUCKET 1214848    // int[782*4608] packed entries s|(dloc<<17) (14.4 MB)
#define OFF_PENC   15629696   // float2[782*3*128] enc partials (2.4 MB)
#define OFF_PCNT   22836608   // int[782*3*128]   count partials (1.2 MB)
#define OFF_PDEC   26440064   // float4[782*3*128] dec partials (4.8 MB)
#define OFF_ENCW   26440064   // enc tables alias pdec head (dead before k_dec writes)

// table layout (dword offsets), identical enc/dec:
//   [0,256)      W1 hi (+bias row: enc k=8, dec k=4)
//   [256,512)    W1 lo (+bias residual row)
//   [512,768)    W2 hi k-tile0   [768,1024)  W2 hi k-tile1
//   [1024,1280)  W2 lo k-tile0   [1280,1536) W2 lo k-tile1
//   [1536,1792)  W3 k-tile0      [1792,2048) W3 k-tile1  (hi only; rows remapped)
//   [2048,2080)  b2 C-frag tab (f32, [hi*16+r])
//   [2080,2112)  b3 tab (remapped rows)

__global__ __launch_bounds__(256) void k_bn_stats(const float* __restrict__ x,
                                                  double* __restrict__ stats) {
    int i = blockIdx.x * 256 + threadIdx.x;
    float4 v = make_float4(0.f, 0.f, 0.f, 0.f);
    if (i < N_NODES) v = ((const float4*)x)[i];
    double a[8];
    a[0] = v.x; a[1] = v.y; a[2] = v.z; a[3] = v.w;
    a[4] = (double)v.x * v.x; a[5] = (double)v.y * v.y;
    a[6] = (double)v.z * v.z; a[7] = (double)v.w * v.w;
    #pragma unroll
    for (int off = 32; off > 0; off >>= 1) {
        #pragma unroll
        for (int j = 0; j < 8; j++) a[j] += __shfl_down(a[j], off);
    }
    __shared__ double smem[4][8];
    int wave = threadIdx.x >> 6;
    int lane = threadIdx.x & 63;
    if (lane == 0) {
        #pragma unroll
        for (int j = 0; j < 8; j++) smem[wave][j] = a[j];
    }
    __syncthreads();
    if (threadIdx.x == 0) {
        #pragma unroll
        for (int j = 0; j < 8; j++) {
            double t = smem[0][j] + smem[1][j] + smem[2][j] + smem[3][j];
            atomicAdd(&stats[j], t);
        }
    }
}

// hi/lo f16 split: part 0 = f16(v), part 1 = f16(v - f16(v)); packs a pair.
static __device__ __forceinline__ uint pk_part(float a, float b, int part) {
    _Float16 ah = (_Float16)a, bh = (_Float16)b;
    if (part) {
        a -= (float)ah; b -= (float)bh;
        ah = (_Float16)a; bh = (_Float16)b;
    }
    return (uint)__builtin_bit_cast(unsigned short, ah) |
           ((uint)__builtin_bit_cast(unsigned short, bh) << 16);
}

// Build all MFMA fragment tables. A[m][k]: m=lane&31, k=8*(lane>>5)+e.
// Runs AFTER k_bn_stats: BN affine folded into enc W1/b1 (exact, f32).
// L1 bias rides a weight ROW (R1-verified): enc A[m][8]=b1', dec A[m][4]=db1,
// hi+lo split -> no b1f register fragment in the hot kernels.
// W3 rows remapped for split atomics: enc out0->row0, out1->row4;
// dec out{0,1,2,3}->rows{0,1,4,5}. W3 is hi-part only (f16 quant ~2e-4 out).
__global__ __launch_bounds__(256) void k_prep(const double* __restrict__ stats,
                                              const float* __restrict__ bn_w,
                                              const float* __restrict__ bn_b,
                                              const float* __restrict__ ew1,
                                              const float* __restrict__ eb1,
                                              const float* __restrict__ ew2,
                                              const float* __restrict__ eb2,
                                              const float* __restrict__ ew3,
                                              const float* __restrict__ eb3,
                                              const float* __restrict__ dw1,
                                              const float* __restrict__ db1,
                                              const float* __restrict__ dw2,
                                              const float* __restrict__ db2,
                                              const float* __restrict__ dw3,
                                              const float* __restrict__ db3,
                                              uint* __restrict__ encw,
                                              uint* __restrict__ decw) {
    int t = threadIdx.x;
    int lane = t >> 2, d = t & 3;
    int hi = lane >> 5, m = lane & 31;

    const double inv_n = 1.0 / (double)N_NODES;
    float sc[4], sh[4];
    #pragma unroll
    for (int dd = 0; dd < 4; dd++) {
        double mu = stats[dd] * inv_n;
        double vr = stats[4 + dd] * inv_n - mu * mu;
        float rs = (float)(1.0 / sqrt(vr + (double)EPS));
        sc[dd] = rs * bn_w[dd];
        sh[dd] = bn_b[dd] - (float)mu * sc[dd];
    }
    // BN-folded enc L1 bias for output channel m
    float b1p = eb1[m];
    #pragma unroll
    for (int dd = 0; dd < 4; dd++) b1p += ew1[dd * 32 + m] * sh[dd];

    int k0 = 8 * hi + 2 * d;
    {   // enc W1 hi+lo (BN-folded weights) + bias row k=8
        float v0 = (k0 < 8) ? ew1[k0 * 32 + m] * sc[k0 & 3]
                            : (k0 == 8 ? b1p : 0.f);
        float v1 = (k0 + 1 < 8) ? ew1[(k0 + 1) * 32 + m] * sc[(k0 + 1) & 3] : 0.f;
        encw[t] = pk_part(v0, v1, 0);
        encw[256 + t] = pk_part(v0, v1, 1);
    }
    {   // dec W1 hi+lo + bias row k=4
        float v0 = (k0 < 4) ? dw1[k0 * 32 + m] : (k0 == 4 ? db1[m] : 0.f);
        float v1 = (k0 + 1 < 4) ? dw1[(k0 + 1) * 32 + m] : 0.f;
        decw[t] = pk_part(v0, v1, 0);
        decw[256 + t] = pk_part(v0, v1, 1);
    }
    #pragma unroll
    for (int tile = 0; tile < 2; tile++) {   // W2 (K=32, 2 k-tiles), hi+lo
        int k = 16 * tile + k0;
        {
            float a = ew2[k * 32 + m], bb = ew2[(k + 1) * 32 + m];
            encw[512 + tile * 256 + t] = pk_part(a, bb, 0);
            encw[1024 + tile * 256 + t] = pk_part(a, bb, 1);
        }
        {
            float a = dw2[k * 32 + m], bb = dw2[(k + 1) * 32 + m];
            decw[512 + tile * 256 + t] = pk_part(a, bb, 0);
            decw[1024 + tile * 256 + t] = pk_part(a, bb, 1);
        }
        {   // enc W3 (32->2), hi only, rows {0,4}
            float a = 0.f, bb = 0.f;
            if (m == 0 || m == 4) {
                int o = m >> 2;
                a = ew3[k * 2 + o]; bb = ew3[(k + 1) * 2 + o];
            }
            encw[1536 + tile * 256 + t] = pk_part(a, bb, 0);
        }
        {   // dec W3 (32->4), hi only, rows {0,1,4,5}
            float a = 0.f, bb = 0.f;
            if ((m & 3) < 2 && m < 6) {
                int o = (m & 1) + 2 * (m >> 2);
                a = dw3[k * 4 + o]; bb = dw3[(k + 1) * 4 + o];
            }
            decw[1536 + tile * 256 + t] = pk_part(a, bb, 0);
        }
    }
    if (t < 32) {   // bias tabs: index hh*16+r, value bias[row(r,hh)]
        int hh = t >> 4, r = t & 15;
        int row = (r & 3) + 8 * (r >> 2) + 4 * hh;
        ((float*)encw)[2048 + t] = eb2[row];
        ((float*)encw)[2080 + t] = (row == 0) ? eb3[0] : (row == 4) ? eb3[1] : 0.f;
        ((float*)decw)[2048 + t] = db2[row];
        ((float*)decw)[2080 + t] =
            ((row & 3) < 2 && row < 6) ? db3[(row & 1) + 2 * (row >> 2)] : 0.f;
    }
}

// S1: bin edges by bucket = dst>>7 into fixed-stride regions, 4B packed
// entries s|(dloc<<17). EPB halved vs R7 for 2x block-level parallelism.
__global__ __launch_bounds__(256) void k_s1(const int* __restrict__ ei,
                                            int* __restrict__ bcnt,
                                            int* __restrict__ bucket_buf) {
    __shared__ int hist[NB];
    __shared__ int base[NB];
    __shared__ int run[NB];
    __shared__ int gbase[NB];
    __shared__ int entries[S1_EPB];
    __shared__ unsigned short bk16[S1_EPB];
    __shared__ int wsum[4];
    int tid = threadIdx.x;
    int e0 = blockIdx.x * S1_EPB;
    for (int i = tid; i < NB; i += 256) hist[i] = 0;
    __syncthreads();
    #pragma unroll
    for (int k = 0; k < S1_EPB / 256; k++) {
        int e = e0 + k * 256 + tid;
        if (e < N_EDGES) atomicAdd(&hist[ei[N_EDGES + e] >> 7], 1);
    }
    __syncthreads();
    int t4 = tid * 4;
    int h0 = (t4 + 0 < NB) ? hist[t4 + 0] : 0;
    int h1 = (t4 + 1 < NB) ? hist[t4 + 1] : 0;
    int h2 = (t4 + 2 < NB) ? hist[t4 + 2] : 0;
    int h3 = (t4 + 3 < NB) ? hist[t4 + 3] : 0;
    int tsum = h0 + h1 + h2 + h3;
    int lane = tid & 63, wv = tid >> 6;
    int xs = tsum;
    #pragma unroll
    for (int off = 1; off < 64; off <<= 1) {
        int u = __shfl_up(xs, off);
        if (lane >= off) xs += u;
    }
    if (lane == 63) wsum[wv] = xs;
    __syncthreads();
    int wo = 0;
    #pragma unroll
    for (int w = 0; w < 4; w++) if (w < wv) wo += wsum[w];
    int texcl = wo + xs - tsum;
    if (t4 + 0 < NB) base[t4 + 0] = texcl;
    if (t4 + 1 < NB) base[t4 + 1] = texcl + h0;
    if (t4 + 2 < NB) base[t4 + 2] = texcl + h0 + h1;
    if (t4 + 3 < NB) base[t4 + 3] = texcl + h0 + h1 + h2;
    __syncthreads();
    for (int i = tid; i < NB; i += 256) {
        int h = hist[i];
        gbase[i] = i * BSTRIDE + (h ? atomicAdd(&bcnt[i], h) : 0);
        run[i] = base[i];
    }
    __syncthreads();
    #pragma unroll
    for (int k = 0; k < S1_EPB / 256; k++) {
        int e = e0 + k * 256 + tid;
        if (e < N_EDGES) {
            int s = ei[e];
            int d = ei[N_EDGES + e];
            int b = d >> 7;
            int r = atomicAdd(&run[b], 1);   // LDS
            entries[r] = s | ((d & 127) << 17);
            bk16[r] = (unsigned short)b;
        }
    }
    __syncthreads();
    int nloc = min(S1_EPB, N_EDGES - e0);
    for (int idx = tid; idx < nloc; idx += 256) {
        int b = bk16[idx];
        bucket_buf[gbase[b] + (idx - base[b])] = entries[idx];
    }
}

// Fused (BN-folded) encoder 8->32->32->2, all three layers on the matrix pipe.
// R3-verified 3-window pipeline. R8: L1 = 2 MFMAs with bias-in-row (no b1f
// fragment), gathers on hi=0 lanes only, launch_bounds(256,4) -> target 4
// waves/SIMD (R7 was reg-capped at 3, occupancy 27%, waves 90% stalled).
__global__ __launch_bounds__(256, 4) void k_enc_partial(const float* __restrict__ x,
                                                        const int* __restrict__ bucket_buf,
                                                        const int* __restrict__ bcnt,
                                                        float2* __restrict__ penc,
                                                        int* __restrict__ pcnt,
                                                        const uint* __restrict__ encw) {
    __shared__ float4 xs[128];
    __shared__ float acc0[128], acc1[128];
    __shared__ int lc[128];
    int b = blockIdx.x, sub = blockIdx.y, tid = threadIdx.x;
    int lane = tid & 63, hi = lane >> 5, col = lane & 31, wv = tid >> 6;
    int cb = bcnt[b];
    int node0 = b << 7;

    if (tid < 128) {
        acc0[tid] = 0.f; acc1[tid] = 0.f; lc[tid] = 0;
        int n = node0 + tid;
        if (n >= N_NODES) n = 0;
        xs[tid] = ((const float4*)x)[n];   // raw x (BN folded into weights)
    }
    __syncthreads();

    const u32x4* W4 = (const u32x4*)encw;
    u32x4 w1h  = W4[lane],       w1l  = W4[64 + lane];
    u32x4 w2h0 = W4[128 + lane], w2h1 = W4[192 + lane];
    u32x4 w2l0 = W4[256 + lane], w2l1 = W4[320 + lane];
    u32x4 w30  = W4[384 + lane], w31  = W4[448 + lane];
    const float* tf = (const float*)encw;
    f32x16 b2f;
    {
        const float4* p2 = (const float4*)(tf + 2048 + hi * 16);
        #pragma unroll
        for (int q = 0; q < 4; q++) {
            float4 c = p2[q];
            b2f[4 * q] = c.x; b2f[4 * q + 1] = c.y; b2f[4 * q + 2] = c.z; b2f[4 * q + 3] = c.w;
        }
    }
    float bc0 = tf[2080 + hi * 16] - b2f[0];
    float* accH = hi ? acc1 : acc0;
    uint z = 0;

    int wb0 = sub * 1536 + wv * 128;
    if (wb0 < cb) {
        const int4* BB = (const int4*)&bucket_buf[b * BSTRIDE];
        int i0 = (wb0 >> 2) + col;
        int4 qa = BB[i0];
        int4 qb = BB[i0 + 128];
        int4 qc = BB[i0 + 256];
        bool act1 = (wb0 + 512) < cb;
        bool act2 = (wb0 + 1024) < cb;

        auto enc_win = [&](const int* ia, const float4* xg, int wb) {
            #pragma unroll
            for (int j = 0; j < 4; j++) {
                u32x4 xf;
                if (hi == 0) {
                    float4 xi = xs[ia[j]];
                    xf.x = pkh(xi.x, xi.y);
                    xf.y = pkh(xi.z, xi.w);
                    xf.z = pkh(xg[j].x - xi.x, xg[j].y - xi.y);
                    xf.w = pkh(xg[j].z - xi.z, xg[j].w - xi.w);
                } else {
                    xf.x = 0x00003C00u;   // k=8 bias row == 1.0
                    xf.y = 0u; xf.z = 0u; xf.w = 0u;
                }
                f32x16 c = {};
                c = MFMA(w1h, xf, c);
                c = MFMA(w1l, xf, c);
                u32x4 f0, f1;
                repack(c, f0, f1, z);
                f32x16 c2 = MFMA(w2h0, f0, b2f);
                c2 = MFMA(w2h1, f1, c2);
                c2 = MFMA(w2l0, f0, c2);
                c2 = MFMA(w2l1, f1, c2);
                u32x4 e0, e1;
                repack(c2, e0, e1, z);
                f32x16 c3 = MFMA(w30, e0, b2f);   // init garbage cancelled by bc0
                c3 = MFMA(w31, e1, c3);
                float o = fmaxf(c3[0] + bc0, 0.f);
                if ((wb + col * 4 + j) < cb) {
                    atomicAdd(&accH[ia[j]], o);
                    if (hi == 0) atomicAdd(&lc[ia[j]], 1);
                }
            }
        };

        int s0[4], s1[4], s2[4], ia0[4], ia1[4], ia2[4];
        float4 xg0[4], xg1[4], xg2[4];
        decode4(qa, s0, ia0);
        if (hi == 0) {
            #pragma unroll
            for (int k = 0; k < 4; k++) xg0[k] = ((const float4*)x)[s0[k]];
        }
        if (act1) {
            decode4(qb, s1, ia1);
            if (hi == 0) {
                #pragma unroll
                for (int k = 0; k < 4; k++) xg1[k] = ((const float4*)x)[s1[k]];
            }
        }
        enc_win(ia0, xg0, wb0);
        if (act2) {
            decode4(qc, s2, ia2);
            if (hi == 0) {
                #pragma unroll
                for (int k = 0; k < 4; k++) xg2[k] = ((const float4*)x)[s2[k]];
            }
        }
        if (act1) enc_win(ia1, xg1, wb0 + 512);
        if (act2) enc_win(ia2, xg2, wb0 + 1024);
    }
    __syncthreads();
    if (tid < 128) {
        int pb = b * NSUB + sub;
        penc[pb * 128 + tid] = make_float2(acc0[tid], acc1[tid]);
        pcnt[pb * 128 + tid] = lc[tid];
    }
}

// sum NSUB chunk-partials per node -> agg1 (mean) + invcnt
__global__ __launch_bounds__(256) void k_reduce_enc_p(const float2* __restrict__ penc,
                                                      const int* __restrict__ pcnt,
                                                      float2* __restrict__ agg1,
                                                      float* __restrict__ invcnt) {
    int i = blockIdx.x * 256 + threadIdx.x;
    if (i >= N_NODES) return;
    int b = i >> 7, l = i & 127;
    float a0 = 0.f, a1 = 0.f;
    int c = 0;
    #pragma unroll
    for (int sub = 0; sub < NSUB; sub++) {
        int idx = (b * NSUB + sub) * 128 + l;
        float2 p = penc[idx];
        a0 += p.x; a1 += p.y;
        c += pcnt[idx];
    }
    float ic = 1.0f / (float)(c > 1 ? c : 1);
    invcnt[i] = ic;
    agg1[i] = make_float2(a0 * ic, a1 * ic);
}

// Fused decoder 4->32->32->4: L1 = 2 MFMAs, bias row k=4 (lanes<32, elem4=1.0).
// Split atomics: hi=0 -> out0,1; hi=1 -> out2,3 (W3 rows 0,1,4,5).
__global__ __launch_bounds__(256, 4) void k_dec_partial(const float2* __restrict__ henc,
                                                        const int* __restrict__ bucket_buf,
                                                        const int* __restrict__ bcnt,
                                                        float4* __restrict__ pdec,
                                                        const uint* __restrict__ decw) {
    __shared__ float2 hld[128];
    __shared__ float a0s[128], a1s[128], a2s[128], a3s[128];
    int b = blockIdx.x, sub = blockIdx.y, tid = threadIdx.x;
    int lane = tid & 63, hi = lane >> 5, col = lane & 31, wv = tid >> 6;
    int cb = bcnt[b];
    int node0 = b << 7;

    if (tid < 128) {
        a0s[tid] = 0.f; a1s[tid] = 0.f; a2s[tid] = 0.f; a3s[tid] = 0.f;
        int n = node0 + tid;
        if (n >= N_NODES) n = 0;
        hld[tid] = henc[n];
    }
    __syncthreads();

    const u32x4* W4 = (const u32x4*)decw;
    u32x4 w1h  = W4[lane],       w1l  = W4[64 + lane];
    u32x4 v2h0 = W4[128 + lane], v2h1 = W4[192 + lane];
    u32x4 v2l0 = W4[256 + lane], v2l1 = W4[320 + lane];
    u32x4 w30  = W4[384 + lane], w31  = W4[448 + lane];
    const float* tf = (const float*)decw;
    f32x16 b2f;
    {
        const float4* p2 = (const float4*)(tf + 2048 + hi * 16);
        #pragma unroll
        for (int q = 0; q < 4; q++) {
            float4 c = p2[q];
            b2f[4 * q] = c.x; b2f[4 * q + 1] = c.y; b2f[4 * q + 2] = c.z; b2f[4 * q + 3] = c.w;
        }
    }
    float bc0 = tf[2080 + hi * 16 + 0] - b2f[0];
    float bc1 = tf[2080 + hi * 16 + 1] - b2f[1];
    float* accA = hi ? a2s : a0s;
    float* accB = hi ? a3s : a1s;
    uint z = 0;

    int wb0 = sub * 1536 + wv * 128;
    if (wb0 < cb) {
        const int4* BB = (const int4*)&bucket_buf[b * BSTRIDE];
        int i0 = (wb0 >> 2) + col;
        int4 qa = BB[i0];
        int4 qb = BB[i0 + 128];
        int4 qc = BB[i0 + 256];
        bool act1 = (wb0 + 512) < cb;
        bool act2 = (wb0 + 1024) < cb;

        auto dec_win = [&](const int* ia, const float2* hj, int wb) {
            #pragma unroll
            for (int j = 0; j < 4; j++) {
                u32x4 xf;
                if (hi == 0) {
                    float2 h2 = hld[ia[j]];
                    xf.x = pkh(h2.x, h2.y);
                    xf.y = pkh(hj[j].x - h2.x, hj[j].y - h2.y);
                    xf.z = 0x00003C00u;   // k=4 bias row == 1.0
                    xf.w = 0u;
                } else {
                    xf.x = 0u; xf.y = 0u; xf.z = 0u; xf.w = 0u;
                }
                f32x16 c = {};
                c = MFMA(w1h, xf, c);
                c = MFMA(w1l, xf, c);
                u32x4 f0, f1;
                repack(c, f0, f1, z);
                f32x16 c2 = MFMA(v2h0, f0, b2f);
                c2 = MFMA(v2h1, f1, c2);
                c2 = MFMA(v2l0, f0, c2);
                c2 = MFMA(v2l1, f1, c2);
                u32x4 e0, e1;
                repack(c2, e0, e1, z);
                f32x16 c3 = MFMA(w30, e0, b2f);
                c3 = MFMA(w31, e1, c3);
                float o0 = c3[0] + bc0;
                float o1 = c3[1] + bc1;
                if ((wb + col * 4 + j) < cb) {
                    atomicAdd(&accA[ia[j]], o0);
                    atomicAdd(&accB[ia[j]], o1);
                }
            }
        };

        int s0[4], s1[4], s2[4], ia0[4], ia1[4], ia2[4];
        float2 hg0[4], hg1[4], hg2[4];
        decode4(qa, s0, ia0);
        if (hi == 0) {
            #pragma unroll
            for (int k = 0; k < 4; k++) hg0[k] = henc[s0[k]];
        }
        if (act1) {
            decode4(qb, s1, ia1);
            if (hi == 0) {
                #pragma unroll
                for (int k = 0; k < 4; k++) hg1[k] = henc[s1[k]];
            }
        }
        dec_win(ia0, hg0, wb0);
        if (act2) {
            decode4(qc, s2, ia2);
            if (hi == 0) {
                #pragma unroll
                for (int k = 0; k < 4; k++) hg2[k] = henc[s2[k]];
            }
        }
        if (act1) dec_win(ia1, hg1, wb0 + 512);
        if (act2) dec_win(ia2, hg2, wb0 + 1024);
    }
    __syncthreads();
    if (tid < 128) {
        int pb = b * NSUB + sub;
        pdec[pb * 128 + tid] = make_float4(a0s[tid], a1s[tid], a2s[tid], a3s[tid]);
    }
}

// sum NSUB chunk-partials per node -> final output (mean)
__global__ __launch_bounds__(256) void k_reduce_dec_p(const float4* __restrict__ pdec,
                                                      const float* __restrict__ invcnt,
                                                      float4* __restrict__ out) {
    int i = blockIdx.x * 256 + threadIdx.x;
    if (i >= N_NODES) return;
    int b = i >> 7, l = i & 127;
    float a0 = 0.f, a1 = 0.f, a2 = 0.f, a3 = 0.f;
    #pragma unroll
    for (int sub = 0; sub < NSUB; sub++) {
        float4 p = pdec[(b * NSUB + sub) * 128 + l];
        a0 += p.x; a1 += p.y; a2 += p.z; a3 += p.w;
    }
    float ic = invcnt[i];
    out[i] = make_float4(a0 * ic, a1 * ic, a2 * ic, a3 * ic);
}

extern "C" void kernel_launch(void* const* d_in, const int* in_sizes, int n_in,
                              void* d_out, int out_size, void* d_ws, size_t ws_size,
                              hipStream_t stream) {
    const float* x    = (const float*)d_in[0];
    const int*   ei   = (const int*)d_in[1];
    const float* bn_w = (const float*)d_in[2];
    const float* bn_b = (const float*)d_in[3];
    const float* ew1  = (const float*)d_in[4];
    const float* eb1  = (const float*)d_in[5];
    const float* ew2  = (const float*)d_in[6];
    const float* eb2  = (const float*)d_in[7];
    const float* ew3  = (const float*)d_in[8];
    const float* eb3  = (const float*)d_in[9];
    const float* dw1  = (const float*)d_in[10];
    const float* db1  = (const float*)d_in[11];
    const float* dw2  = (const float*)d_in[12];
    const float* db2  = (const float*)d_in[13];
    const float* dw3  = (const float*)d_in[14];
    const float* db3  = (const float*)d_in[15];

    char* ws = (char*)d_ws;
    double* stats      = (double*)(ws + OFF_STATS);
    int*    bcnt       = (int*)(ws + OFF_BCNT);
    float*  invcnt     = (float*)(ws + OFF_INVCNT);
    float2* agg1       = (float2*)(ws + OFF_AGG1);
    uint*   decw       = (uint*)(ws + OFF_DECW);
    int*    bucket_buf = (int*)(ws + OFF_BUCKET);
    float2* penc       = (float2*)(ws + OFF_PENC);
    int*    pcnt       = (int*)(ws + OFF_PCNT);
    float4* pdec       = (float4*)(ws + OFF_PDEC);
    uint*   encw       = (uint*)(ws + OFF_ENCW);
    float4* out        = (float4*)d_out;

    // zero: stats + bucket counts, contiguous [0, 5120)
    hipMemsetAsync(ws, 0, 5120, stream);

    k_bn_stats<<<NODE_BLOCKS, 256, 0, stream>>>(x, stats);
    k_prep<<<1, 256, 0, stream>>>(stats, bn_w, bn_b, ew1, eb1, ew2, eb2, ew3, eb3,
                                  dw1, db1, dw2, db2, dw3, db3, encw, decw);
    k_s1<<<S1_BLOCKS, 256, 0, stream>>>(ei, bcnt, bucket_buf);
    k_enc_partial<<<dim3(NB, NSUB), 256, 0, stream>>>(x, bucket_buf, bcnt,
                                                      penc, pcnt, encw);
    k_reduce_enc_p<<<NODE_BLOCKS, 256, 0, stream>>>(penc, pcnt, agg1, invcnt);
    k_dec_partial<<<dim3(NB, NSUB), 256, 0, stream>>>(agg1, bucket_buf, bcnt, pdec, decw);
    k_reduce_dec_p<<<NODE_BLOCKS, 256, 0, stream>>>(pdec, invcnt, out);
}

// Round 9
// 310.833 us; speedup vs baseline: 1.0001x; 1.0001x over previous
//
#include <hip/hip_runtime.h>

#define N_NODES 100000
#define N_EDGES 3200000
#define EPS 1e-5f
#define NB 782            // buckets of 128 nodes (dst >> 7)
#define BSTRIDE 4608      // fixed bucket region: mean 4096 + 8 sigma
#define S1_EPB 8192
#define S1_BLOCKS 391

typedef unsigned int uint;
typedef uint u32x4 __attribute__((ext_vector_type(4)));
typedef _Float16 f16x8 __attribute__((ext_vector_type(8)));
typedef float f32x16 __attribute__((ext_vector_type(16)));

static __device__ __forceinline__ f16x8 as_h8(u32x4 u) { return __builtin_bit_cast(f16x8, u); }
static __device__ __forceinline__ uint pkh(float a, float b) {
    return __builtin_bit_cast(uint, __builtin_amdgcn_cvt_pkrtz(a, b));
}
// v_permlane32_swap_b32: a' = [a.lo32 | b.lo32], b' = [a.hi32 | b.hi32]
// volatile + this exact usage is the R1-R3/R7/R8 verified pattern. Do NOT
// touch: R5/R6 experiments around this instruction failed verification twice.
static __device__ __forceinline__ void swap32(uint& a, uint& b) {
    asm volatile("v_permlane32_swap_b32 %0, %1" : "+v"(a), "+v"(b));
}
// packed f16 relu: max(x, 0) on both halves. rtz-then-relu == relu-then-rtz.
static __device__ __forceinline__ uint prelu(uint u, uint z) {
    uint r;
    asm("v_pk_max_f16 %0, %1, %2" : "=v"(r) : "v"(u), "v"(z));
    return r;
}

#define MFMA(A, B, C) __builtin_amdgcn_mfma_f32_32x32x16_f16(as_h8(A), as_h8(B), (C), 0, 0, 0)

// Repack MFMA C (32 rows x 32 edge-cols, row=(r&3)+8*(r>>2)+4*hi) into the two
// B-fragments for the next K=32 MFMA pair, applying relu in packed f16.
// Verified pattern (R1-R3,R7,R8): pkh pairs + 4x permlane32_swap.
static __device__ __forceinline__ void repack(const f32x16& c, u32x4& f0, u32x4& f1, uint z) {
    uint p0 = prelu(pkh(c[0], c[1]), z),   p1 = prelu(pkh(c[2], c[3]), z);
    uint q0 = prelu(pkh(c[4], c[5]), z),   q1 = prelu(pkh(c[6], c[7]), z);
    uint p2 = prelu(pkh(c[8], c[9]), z),   p3 = prelu(pkh(c[10], c[11]), z);
    uint q2 = prelu(pkh(c[12], c[13]), z), q3 = prelu(pkh(c[14], c[15]), z);
    swap32(p0, q0); swap32(p1, q1);
    swap32(p2, q2); swap32(p3, q3);
    f0.x = p0; f0.y = p1; f0.z = q0; f0.w = q1;
    f1.x = p2; f1.y = p3; f1.z = q2; f1.w = q3;
}

// ---- workspace layout (bytes) ----
#define OFF_STATS  0          // 8 doubles (bn sums)          [zeroed]
#define OFF_BCNT   1024       // int[782] bucket counts       [zeroed]
#define OFF_INVCNT 5120       // float[100000]
#define OFF_AGG1   405120     // float2[100000]
#define OFF_DECW   1205120    // dec MFMA tables: 2112 dwords = 8448B
#define OFF_BUCKET 1214848    // int[782*4608] packed entries s|(dloc<<17) (14.4 MB)
#define OFF_ENCW   15629696   // enc MFMA tables: 2112 dwords

// table layout (dword offsets), identical enc/dec:
//   [0,256)      W1 hi (+bias row: enc k=8, dec k=4)
//   [256,512)    W1 lo (+bias residual row)
//   [512,768)    W2 hi k-tile0   [768,1024)  W2 hi k-tile1
//   [1024,1280)  W2 lo k-tile0   [1280,1536) W2 lo k-tile1
//   [1536,1792)  W3 k-tile0      [1792,2048) W3 k-tile1  (hi only; rows remapped)
//   [2048,2080)  b2 C-frag tab (f32, [hi*16+r])
//   [2080,2112)  b3 tab (remapped rows)

// hi/lo f16 split: part 0 = f16(v), part 1 = f16(v - f16(v)); packs a pair.
static __device__ __forceinline__ uint pk_part(float a, float b, int part) {
    _Float16 ah = (_Float16)a, bh = (_Float16)b;
    if (part) {
        a -= (float)ah; b -= (float)bh;
        ah = (_Float16)a; bh = (_Float16)b;
    }
    return (uint)__builtin_bit_cast(unsigned short, ah) |
           ((uint)__builtin_bit_cast(unsigned short, bh) << 16);
}

// Build all MFMA fragment tables (R8-verified). A[m][k]: m=lane&31, k=8*hi+e.
// L1 bias rides a weight ROW: enc A[m][8]=BN-folded b1, dec A[m][4]=db1.
// W3 rows remapped for split atomics; W3 hi-part only.
__global__ __launch_bounds__(256) void k_prep(const double* __restrict__ stats,
                                              const float* __restrict__ bn_w,
                                              const float* __restrict__ bn_b,
                                              const float* __restrict__ ew1,
                                              const float* __restrict__ eb1,
                                              const float* __restrict__ ew2,
                                              const float* __restrict__ eb2,
                                              const float* __restrict__ ew3,
                                              const float* __restrict__ eb3,
                                              const float* __restrict__ dw1,
                                              const float* __restrict__ db1,
                                              const float* __restrict__ dw2,
                                              const float* __restrict__ db2,
                                              const float* __restrict__ dw3,
                                              const float* __restrict__ db3,
                                              uint* __restrict__ encw,
                                              uint* __restrict__ decw) {
    int t = threadIdx.x;
    int lane = t >> 2, d = t & 3;
    int hi = lane >> 5, m = lane & 31;

    const double inv_n = 1.0 / (double)N_NODES;
    float sc[4], sh[4];
    #pragma unroll
    for (int dd = 0; dd < 4; dd++) {
        double mu = stats[dd] * inv_n;
        double vr = stats[4 + dd] * inv_n - mu * mu;
        float rs = (float)(1.0 / sqrt(vr + (double)EPS));
        sc[dd] = rs * bn_w[dd];
        sh[dd] = bn_b[dd] - (float)mu * sc[dd];
    }
    float b1p = eb1[m];
    #pragma unroll
    for (int dd = 0; dd < 4; dd++) b1p += ew1[dd * 32 + m] * sh[dd];

    int k0 = 8 * hi + 2 * d;
    {   // enc W1 hi+lo (BN-folded weights) + bias row k=8
        float v0 = (k0 < 8) ? ew1[k0 * 32 + m] * sc[k0 & 3]
                            : (k0 == 8 ? b1p : 0.f);
        float v1 = (k0 + 1 < 8) ? ew1[(k0 + 1) * 32 + m] * sc[(k0 + 1) & 3] : 0.f;
        encw[t] = pk_part(v0, v1, 0);
        encw[256 + t] = pk_part(v0, v1, 1);
    }
    {   // dec W1 hi+lo + bias row k=4
        float v0 = (k0 < 4) ? dw1[k0 * 32 + m] : (k0 == 4 ? db1[m] : 0.f);
        float v1 = (k0 + 1 < 4) ? dw1[(k0 + 1) * 32 + m] : 0.f;
        decw[t] = pk_part(v0, v1, 0);
        decw[256 + t] = pk_part(v0, v1, 1);
    }
    #pragma unroll
    for (int tile = 0; tile < 2; tile++) {   // W2 (K=32, 2 k-tiles), hi+lo
        int k = 16 * tile + k0;
        {
            float a = ew2[k * 32 + m], bb = ew2[(k + 1) * 32 + m];
            encw[512 + tile * 256 + t] = pk_part(a, bb, 0);
            encw[1024 + tile * 256 + t] = pk_part(a, bb, 1);
        }
        {
            float a = dw2[k * 32 + m], bb = dw2[(k + 1) * 32 + m];
            decw[512 + tile * 256 + t] = pk_part(a, bb, 0);
            decw[1024 + tile * 256 + t] = pk_part(a, bb, 1);
        }
        {   // enc W3 (32->2), hi only, rows {0,4}
            float a = 0.f, bb = 0.f;
            if (m == 0 || m == 4) {
                int o = m >> 2;
                a = ew3[k * 2 + o]; bb = ew3[(k + 1) * 2 + o];
            }
            encw[1536 + tile * 256 + t] = pk_part(a, bb, 0);
        }
        {   // dec W3 (32->4), hi only, rows {0,1,4,5}
            float a = 0.f, bb = 0.f;
            if ((m & 3) < 2 && m < 6) {
                int o = (m & 1) + 2 * (m >> 2);
                a = dw3[k * 4 + o]; bb = dw3[(k + 1) * 4 + o];
            }
            decw[1536 + tile * 256 + t] = pk_part(a, bb, 0);
        }
    }
    if (t < 32) {   // bias tabs: index hh*16+r, value bias[row(r,hh)]
        int hh = t >> 4, r = t & 15;
        int row = (r & 3) + 8 * (r >> 2) + 4 * hh;
        ((float*)encw)[2048 + t] = eb2[row];
        ((float*)encw)[2080 + t] = (row == 0) ? eb3[0] : (row == 4) ? eb3[1] : 0.f;
        ((float*)decw)[2048 + t] = db2[row];
        ((float*)decw)[2080 + t] =
            ((row & 3) < 2 && row < 6) ? db3[(row & 1) + 2 * (row >> 2)] : 0.f;
    }
}

// S1 + fused BN stats: each block first accumulates its 256-node slice of the
// BN sums (independent work, removes one kernel launch), then bins its 8192
// edges by bucket = dst>>7 (R7-verified binning code, EPB back to 8192).
__global__ __launch_bounds__(256) void k_s1(const float* __restrict__ x,
                                            double* __restrict__ stats,
                                            const int* __restrict__ ei,
                                            int* __restrict__ bcnt,
                                            int* __restrict__ bucket_buf) {
    __shared__ int hist[NB];
    __shared__ int base[NB];
    __shared__ int run[NB];
    __shared__ int gbase[NB];
    __shared__ int entries[S1_EPB];
    __shared__ unsigned short bk16[S1_EPB];
    __shared__ int wsum[4];
    __shared__ double smem_bn[4][8];
    int tid = threadIdx.x;

    {   // ---- BN stats slice ----
        int i = blockIdx.x * 256 + tid;
        float4 v = make_float4(0.f, 0.f, 0.f, 0.f);
        if (i < N_NODES) v = ((const float4*)x)[i];
        double a[8];
        a[0] = v.x; a[1] = v.y; a[2] = v.z; a[3] = v.w;
        a[4] = (double)v.x * v.x; a[5] = (double)v.y * v.y;
        a[6] = (double)v.z * v.z; a[7] = (double)v.w * v.w;
        #pragma unroll
        for (int off = 32; off > 0; off >>= 1) {
            #pragma unroll
            for (int j = 0; j < 8; j++) a[j] += __shfl_down(a[j], off);
        }
        int wave = tid >> 6, lane = tid & 63;
        if (lane == 0) {
            #pragma unroll
            for (int j = 0; j < 8; j++) smem_bn[wave][j] = a[j];
        }
        __syncthreads();
        if (tid == 0) {
            #pragma unroll
            for (int j = 0; j < 8; j++) {
                double t2 = smem_bn[0][j] + smem_bn[1][j] + smem_bn[2][j] + smem_bn[3][j];
                atomicAdd(&stats[j], t2);
            }
        }
    }

    // ---- edge binning ----
    int e0 = blockIdx.x * S1_EPB;
    for (int i = tid; i < NB; i += 256) hist[i] = 0;
    __syncthreads();
    #pragma unroll
    for (int k = 0; k < S1_EPB / 256; k++) {
        int e = e0 + k * 256 + tid;
        if (e < N_EDGES) atomicAdd(&hist[ei[N_EDGES + e] >> 7], 1);
    }
    __syncthreads();
    int t4 = tid * 4;
    int h0 = (t4 + 0 < NB) ? hist[t4 + 0] : 0;
    int h1 = (t4 + 1 < NB) ? hist[t4 + 1] : 0;
    int h2 = (t4 + 2 < NB) ? hist[t4 + 2] : 0;
    int h3 = (t4 + 3 < NB) ? hist[t4 + 3] : 0;
    int tsum = h0 + h1 + h2 + h3;
    int lane = tid & 63, wv = tid >> 6;
    int xs = tsum;
    #pragma unroll
    for (int off = 1; off < 64; off <<= 1) {
        int u = __shfl_up(xs, off);
        if (lane >= off) xs += u;
    }
    if (lane == 63) wsum[wv] = xs;
    __syncthreads();
    int wo = 0;
    #pragma unroll
    for (int w = 0; w < 4; w++) if (w < wv) wo += wsum[w];
    int texcl = wo + xs - tsum;
    if (t4 + 0 < NB) base[t4 + 0] = texcl;
    if (t4 + 1 < NB) base[t4 + 1] = texcl + h0;
    if (t4 + 2 < NB) base[t4 + 2] = texcl + h0 + h1;
    if (t4 + 3 < NB) base[t4 + 3] = texcl + h0 + h1 + h2;
    __syncthreads();
    for (int i = tid; i < NB; i += 256) {
        int h = hist[i];
        gbase[i] = i * BSTRIDE + (h ? atomicAdd(&bcnt[i], h) : 0);
        run[i] = base[i];
    }
    __syncthreads();
    #pragma unroll
    for (int k = 0; k < S1_EPB / 256; k++) {
        int e = e0 + k * 256 + tid;
        if (e < N_EDGES) {
            int s = ei[e];
            int d = ei[N_EDGES + e];
            int b = d >> 7;
            int r = atomicAdd(&run[b], 1);   // LDS
            entries[r] = s | ((d & 127) << 17);
            bk16[r] = (unsigned short)b;
        }
    }
    __syncthreads();
    int nloc = min(S1_EPB, N_EDGES - e0);
    for (int idx = tid; idx < nloc; idx += 256) {
        int b = bk16[idx];
        bucket_buf[gbase[b] + (idx - base[b])] = entries[idx];
    }
}

// Fused (BN-folded) encoder 8->32->32->2, all three layers on the matrix pipe.
// NSUB=1: ONE block per bucket; each wave walks 9 windows of 4 tiles with
// depth-1 prefetch. The block's partial IS the total -> writes agg1/invcnt
// directly (reduce kernel eliminated). Hot-loop tile math = R8 verified.
__global__ __launch_bounds__(256, 4) void k_enc_partial(const float* __restrict__ x,
                                                        const int* __restrict__ bucket_buf,
                                                        const int* __restrict__ bcnt,
                                                        float2* __restrict__ agg1,
                                                        float* __restrict__ invcnt,
                                                        const uint* __restrict__ encw) {
    __shared__ float4 xs[128];
    __shared__ float acc0[128], acc1[128];
    __shared__ int lc[128];
    int b = blockIdx.x, tid = threadIdx.x;
    int lane = tid & 63, hi = lane >> 5, col = lane & 31, wv = tid >> 6;
    int cb = bcnt[b];
    int node0 = b << 7;

    if (tid < 128) {
        acc0[tid] = 0.f; acc1[tid] = 0.f; lc[tid] = 0;
        int n = node0 + tid;
        if (n >= N_NODES) n = 0;
        xs[tid] = ((const float4*)x)[n];   // raw x (BN folded into weights)
    }
    __syncthreads();

    const u32x4* W4 = (const u32x4*)encw;
    u32x4 w1h  = W4[lane],       w1l  = W4[64 + lane];
    u32x4 w2h0 = W4[128 + lane], w2h1 = W4[192 + lane];
    u32x4 w2l0 = W4[256 + lane], w2l1 = W4[320 + lane];
    u32x4 w30  = W4[384 + lane], w31  = W4[448 + lane];
    const float* tf = (const float*)encw;
    f32x16 b2f;
    {
        const float4* p2 = (const float4*)(tf + 2048 + hi * 16);
        #pragma unroll
        for (int q = 0; q < 4; q++) {
            float4 c = p2[q];
            b2f[4 * q] = c.x; b2f[4 * q + 1] = c.y; b2f[4 * q + 2] = c.z; b2f[4 * q + 3] = c.w;
        }
    }
    float bc0 = tf[2048 + 32 + hi * 16] - b2f[0];
    float* accH = hi ? acc1 : acc0;
    uint z = 0;

    // one tile of 32 edges (R8-verified arithmetic)
    auto tile = [&](int ian, const float4& g, int slot) {
        u32x4 xf;
        if (hi == 0) {
            float4 xi = xs[ian];
            xf.x = pkh(xi.x, xi.y);
            xf.y = pkh(xi.z, xi.w);
            xf.z = pkh(g.x - xi.x, g.y - xi.y);
            xf.w = pkh(g.z - xi.z, g.w - xi.w);
        } else {
            xf.x = 0x00003C00u;   // k=8 bias row == 1.0
            xf.y = 0u; xf.z = 0u; xf.w = 0u;
        }
        f32x16 c = {};
        c = MFMA(w1h, xf, c);
        c = MFMA(w1l, xf, c);
        u32x4 f0, f1;
        repack(c, f0, f1, z);
        f32x16 c2 = MFMA(w2h0, f0, b2f);
        c2 = MFMA(w2h1, f1, c2);
        c2 = MFMA(w2l0, f0, c2);
        c2 = MFMA(w2l1, f1, c2);
        u32x4 e0, e1;
        repack(c2, e0, e1, z);
        f32x16 c3 = MFMA(w30, e0, b2f);   // init garbage cancelled by bc0
        c3 = MFMA(w31, e1, c3);
        float o = fmaxf(c3[0] + bc0, 0.f);
        if (slot < cb) {
            atomicAdd(&accH[ian], o);
            if (hi == 0) atomicAdd(&lc[ian], 1);
        }
    };

    int wb = wv * 128;
    if (wb < cb) {
        const int4* BB = (const int4*)&bucket_buf[b * BSTRIDE];
        int i0 = wv * 32 + col;
        // prefetch window 0
        int iaA, iaB, iaC, iaD;
        float4 gA, gB, gC, gD;
        {
            int4 q = BB[i0];
            int s0 = q.x & 0x1FFFF, s1 = q.y & 0x1FFFF;
            int s2 = q.z & 0x1FFFF, s3 = q.w & 0x1FFFF;
            if (s0 >= N_NODES) s0 = 0;
            if (s1 >= N_NODES) s1 = 0;
            if (s2 >= N_NODES) s2 = 0;
            if (s3 >= N_NODES) s3 = 0;
            iaA = (q.x >> 17) & 127; iaB = (q.y >> 17) & 127;
            iaC = (q.z >> 17) & 127; iaD = (q.w >> 17) & 127;
            if (hi == 0) {
                gA = ((const float4*)x)[s0];
                gB = ((const float4*)x)[s1];
                gC = ((const float4*)x)[s2];
                gD = ((const float4*)x)[s3];
            }
        }
        #pragma unroll 1
        for (int w = 0; ; w++) {
            int wbn = wb + 512;
            bool more = wbn < cb;
            int nA = 0, nB = 0, nC = 0, nD = 0;
            float4 hA, hB, hC, hD;
            if (more) {
                int4 q = BB[i0 + (w + 1) * 128];
                int s0 = q.x & 0x1FFFF, s1 = q.y & 0x1FFFF;
                int s2 = q.z & 0x1FFFF, s3 = q.w & 0x1FFFF;
                if (s0 >= N_NODES) s0 = 0;
                if (s1 >= N_NODES) s1 = 0;
                if (s2 >= N_NODES) s2 = 0;
                if (s3 >= N_NODES) s3 = 0;
                nA = (q.x >> 17) & 127; nB = (q.y >> 17) & 127;
                nC = (q.z >> 17) & 127; nD = (q.w >> 17) & 127;
                if (hi == 0) {
                    hA = ((const float4*)x)[s0];
                    hB = ((const float4*)x)[s1];
                    hC = ((const float4*)x)[s2];
                    hD = ((const float4*)x)[s3];
                }
            }
            int sl = wb + col * 4;
            tile(iaA, gA, sl);
            tile(iaB, gB, sl + 1);
            tile(iaC, gC, sl + 2);
            tile(iaD, gD, sl + 3);
            if (!more) break;
            iaA = nA; iaB = nB; iaC = nC; iaD = nD;
            gA = hA; gB = hB; gC = hC; gD = hD;
            wb = wbn;
        }
    }
    __syncthreads();
    if (tid < 128) {
        int n = node0 + tid;
        if (n < N_NODES) {
            int c = lc[tid];
            float ic = 1.0f / (float)(c > 1 ? c : 1);
            invcnt[n] = ic;
            agg1[n] = make_float2(acc0[tid] * ic, acc1[tid] * ic);
        }
    }
}

// Fused decoder 4->32->32->4, same NSUB=1 structure; writes final out directly.
// Split atomics: hi=0 -> out0,1; hi=1 -> out2,3 (W3 rows 0,1,4,5).
__global__ __launch_bounds__(256, 4) void k_dec_partial(const float2* __restrict__ henc,
                                                        const int* __restrict__ bucket_buf,
                                                        const int* __restrict__ bcnt,
                                                        const float* __restrict__ invcnt,
                                                        float4* __restrict__ out,
                                                        const uint* __restrict__ decw) {
    __shared__ float2 hld[128];
    __shared__ float a0s[128], a1s[128], a2s[128], a3s[128];
    int b = blockIdx.x, tid = threadIdx.x;
    int lane = tid & 63, hi = lane >> 5, col = lane & 31, wv = tid >> 6;
    int cb = bcnt[b];
    int node0 = b << 7;

    if (tid < 128) {
        a0s[tid] = 0.f; a1s[tid] = 0.f; a2s[tid] = 0.f; a3s[tid] = 0.f;
        int n = node0 + tid;
        if (n >= N_NODES) n = 0;
        hld[tid] = henc[n];
    }
    __syncthreads();

    const u32x4* W4 = (const u32x4*)decw;
    u32x4 w1h  = W4[lane],       w1l  = W4[64 + lane];
    u32x4 v2h0 = W4[128 + lane], v2h1 = W4[192 + lane];
    u32x4 v2l0 = W4[256 + lane], v2l1 = W4[320 + lane];
    u32x4 w30  = W4[384 + lane], w31  = W4[448 + lane];
    const float* tf = (const float*)decw;
    f32x16 b2f;
    {
        const float4* p2 = (const float4*)(tf + 2048 + hi * 16);
        #pragma unroll
        for (int q = 0; q < 4; q++) {
            float4 c = p2[q];
            b2f[4 * q] = c.x; b2f[4 * q + 1] = c.y; b2f[4 * q + 2] = c.z; b2f[4 * q + 3] = c.w;
        }
    }
    float bc0 = tf[2048 + 32 + hi * 16 + 0] - b2f[0];
    float bc1 = tf[2048 + 32 + hi * 16 + 1] - b2f[1];
    float* accA = hi ? a2s : a0s;
    float* accB = hi ? a3s : a1s;
    uint z = 0;

    auto tile = [&](int ian, const float2& g, int slot) {
        u32x4 xf;
        if (hi == 0) {
            float2 h2 = hld[ian];
            xf.x = pkh(h2.x, h2.y);
            xf.y = pkh(g.x - h2.x, g.y - h2.y);
            xf.z = 0x00003C00u;   // k=4 bias row == 1.0
            xf.w = 0u;
        } else {
            xf.x = 0u; xf.y = 0u; xf.z = 0u; xf.w = 0u;
        }
        f32x16 c = {};
        c = MFMA(w1h, xf, c);
        c = MFMA(w1l, xf, c);
        u32x4 f0, f1;
        repack(c, f0, f1, z);
        f32x16 c2 = MFMA(v2h0, f0, b2f);
        c2 = MFMA(v2h1, f1, c2);
        c2 = MFMA(v2l0, f0, c2);
        c2 = MFMA(v2l1, f1, c2);
        u32x4 e0, e1;
        repack(c2, e0, e1, z);
        f32x16 c3 = MFMA(w30, e0, b2f);
        c3 = MFMA(w31, e1, c3);
        float o0 = c3[0] + bc0;
        float o1 = c3[1] + bc1;
        if (slot < cb) {
            atomicAdd(&accA[ian], o0);
            atomicAdd(&accB[ian], o1);
        }
    };

    int wb = wv * 128;
    if (wb < cb) {
        const int4* BB = (const int4*)&bucket_buf[b * BSTRIDE];
        int i0 = wv * 32 + col;
        int iaA, iaB, iaC, iaD;
        float2 gA, gB, gC, gD;
        {
            int4 q = BB[i0];
            int s0 = q.x & 0x1FFFF, s1 = q.y & 0x1FFFF;
            int s2 = q.z & 0x1FFFF, s3 = q.w & 0x1FFFF;
            if (s0 >= N_NODES) s0 = 0;
            if (s1 >= N_NODES) s1 = 0;
            if (s2 >= N_NODES) s2 = 0;
            if (s3 >= N_NODES) s3 = 0;
            iaA = (q.x >> 17) & 127; iaB = (q.y >> 17) & 127;
            iaC = (q.z >> 17) & 127; iaD = (q.w >> 17) & 127;
            if (hi == 0) {
                gA = henc[s0]; gB = henc[s1]; gC = henc[s2]; gD = henc[s3];
            }
        }
        #pragma unroll 1
        for (int w = 0; ; w++) {
            int wbn = wb + 512;
            bool more = wbn < cb;
            int nA = 0, nB = 0, nC = 0, nD = 0;
            float2 hA, hB, hC, hD;
            if (more) {
                int4 q = BB[i0 + (w + 1) * 128];
                int s0 = q.x & 0x1FFFF, s1 = q.y & 0x1FFFF;
                int s2 = q.z & 0x1FFFF, s3 = q.w & 0x1FFFF;
                if (s0 >= N_NODES) s0 = 0;
                if (s1 >= N_NODES) s1 = 0;
                if (s2 >= N_NODES) s2 = 0;
                if (s3 >= N_NODES) s3 = 0;
                nA = (q.x >> 17) & 127; nB = (q.y >> 17) & 127;
                nC = (q.z >> 17) & 127; nD = (q.w >> 17) & 127;
                if (hi == 0) {
                    hA = henc[s0]; hB = henc[s1]; hC = henc[s2]; hD = henc[s3];
                }
            }
            int sl = wb + col * 4;
            tile(iaA, gA, sl);
            tile(iaB, gB, sl + 1);
            tile(iaC, gC, sl + 2);
            tile(iaD, gD, sl + 3);
            if (!more) break;
            iaA = nA; iaB = nB; iaC = nC; iaD = nD;
            gA = hA; gB = hB; gC = hC; gD = hD;
            wb = wbn;
        }
    }
    __syncthreads();
    if (tid < 128) {
        int n = node0 + tid;
        if (n < N_NODES) {
            float ic = invcnt[n];
            out[n] = make_float4(a0s[tid] * ic, a1s[tid] * ic,
                                 a2s[tid] * ic, a3s[tid] * ic);
        }
    }
}

extern "C" void kernel_launch(void* const* d_in, const int* in_sizes, int n_in,
                              void* d_out, int out_size, void* d_ws, size_t ws_size,
                              hipStream_t stream) {
    const float* x    = (const float*)d_in[0];
    const int*   ei   = (const int*)d_in[1];
    const float* bn_w = (const float*)d_in[2];
    const float* bn_b = (const float*)d_in[3];
    const float* ew1  = (const float*)d_in[4];
    const float* eb1  = (const float*)d_in[5];
    const float* ew2  = (const float*)d_in[6];
    const float* eb2  = (const float*)d_in[7];
    const float* ew3  = (const float*)d_in[8];
    const float* eb3  = (const float*)d_in[9];
    const float* dw1  = (const float*)d_in[10];
    const float* db1  = (const float*)d_in[11];
    const float* dw2  = (const float*)d_in[12];
    const float* db2  = (const float*)d_in[13];
    const float* dw3  = (const float*)d_in[14];
    const float* db3  = (const float*)d_in[15];

    char* ws = (char*)d_ws;
    double* stats      = (double*)(ws + OFF_STATS);
    int*    bcnt       = (int*)(ws + OFF_BCNT);
    float*  invcnt     = (float*)(ws + OFF_INVCNT);
    float2* agg1       = (float2*)(ws + OFF_AGG1);
    uint*   decw       = (uint*)(ws + OFF_DECW);
    int*    bucket_buf = (int*)(ws + OFF_BUCKET);
    uint*   encw       = (uint*)(ws + OFF_ENCW);
    float4* out        = (float4*)d_out;

    // zero: stats + bucket counts, contiguous [0, 5120)
    hipMemsetAsync(ws, 0, 5120, stream);

    k_s1<<<S1_BLOCKS, 256, 0, stream>>>(x, stats, ei, bcnt, bucket_buf);
    k_prep<<<1, 256, 0, stream>>>(stats, bn_w, bn_b, ew1, eb1, ew2, eb2, ew3, eb3,
                                  dw1, db1, dw2, db2, dw3, db3, encw, decw);
    k_enc_partial<<<NB, 256, 0, stream>>>(x, bucket_buf, bcnt, agg1, invcnt, encw);
    k_dec_partial<<<NB, 256, 0, stream>>>(agg1, bucket_buf, bcnt, invcnt, out, decw);
}

// Round 10
// 294.384 us; speedup vs baseline: 1.0560x; 1.0559x over previous
//
#include <hip/hip_runtime.h>

#define N_NODES 100000
#define N_EDGES 3200000
#define EPS 1e-5f
#define NODE_BLOCKS 391   // ceil(100000/256)
#define NB 782            // buckets of 128 nodes (dst >> 7)
#define BSTRIDE 4608      // fixed bucket region: mean 4096 + 8 sigma
#define NSUB 3            // chunks of 1536 slots per bucket (3*1536 = 4608)
#define S1_EPB 8192
#define S1_BLOCKS 391

typedef unsigned int uint;
typedef uint u32x4 __attribute__((ext_vector_type(4)));
typedef _Float16 f16x8 __attribute__((ext_vector_type(8)));
typedef float f32x16 __attribute__((ext_vector_type(16)));

static __device__ __forceinline__ f16x8 as_h8(u32x4 u) { return __builtin_bit_cast(f16x8, u); }
static __device__ __forceinline__ uint pkh(float a, float b) {
    return __builtin_bit_cast(uint, __builtin_amdgcn_cvt_pkrtz(a, b));
}
// v_permlane32_swap_b32: a' = [a.lo32 | b.lo32], b' = [a.hi32 | b.hi32]
// volatile + this exact usage is the R1-R3/R7/R8 verified pattern. Do NOT
// touch: R5/R6 experiments around this instruction failed verification twice.
static __device__ __forceinline__ void swap32(uint& a, uint& b) {
    asm volatile("v_permlane32_swap_b32 %0, %1" : "+v"(a), "+v"(b));
}
// packed f16 relu: max(x, 0) on both halves. rtz-then-relu == relu-then-rtz.
static __device__ __forceinline__ uint prelu(uint u, uint z) {
    uint r;
    asm("v_pk_max_f16 %0, %1, %2" : "=v"(r) : "v"(u), "v"(z));
    return r;
}

#define MFMA(A, B, C) __builtin_amdgcn_mfma_f32_32x32x16_f16(as_h8(A), as_h8(B), (C), 0, 0, 0)

// Repack MFMA C (32 rows x 32 edge-cols, row=(r&3)+8*(r>>2)+4*hi) into the two
// B-fragments for the next K=32 MFMA pair, applying relu in packed f16.
// Verified pattern (R1-R3,R7,R8,R9): pkh pairs + 4x permlane32_swap.
static __device__ __forceinline__ void repack(const f32x16& c, u32x4& f0, u32x4& f1, uint z) {
    uint p0 = prelu(pkh(c[0], c[1]), z),   p1 = prelu(pkh(c[2], c[3]), z);
    uint q0 = prelu(pkh(c[4], c[5]), z),   q1 = prelu(pkh(c[6], c[7]), z);
    uint p2 = prelu(pkh(c[8], c[9]), z),   p3 = prelu(pkh(c[10], c[11]), z);
    uint q2 = prelu(pkh(c[12], c[13]), z), q3 = prelu(pkh(c[14], c[15]), z);
    swap32(p0, q0); swap32(p1, q1);
    swap32(p2, q2); swap32(p3, q3);
    f0.x = p0; f0.y = p1; f0.z = q0; f0.w = q1;
    f1.x = p2; f1.y = p3; f1.z = q2; f1.w = q3;
}

static __device__ __forceinline__ void decode4(const int4& q, int* ss, int* ia) {
    int e0 = q.x, e1 = q.y, e2 = q.z, e3 = q.w;
    ss[0] = e0 & 0x1FFFF; ia[0] = (e0 >> 17) & 127;
    ss[1] = e1 & 0x1FFFF; ia[1] = (e1 >> 17) & 127;
    ss[2] = e2 & 0x1FFFF; ia[2] = (e2 >> 17) & 127;
    ss[3] = e3 & 0x1FFFF; ia[3] = (e3 >> 17) & 127;
    #pragma unroll
    for (int k = 0; k < 4; k++)
        if (ss[k] >= N_NODES) ss[k] = 0;   // slots >= cb hold stale garbage
}

// ---- workspace layout (bytes) ----
#define OFF_STATS  0          // 8 doubles (bn sums)          [zeroed]
#define OFF_BCNT   1024       // int[782] bucket counts       [zeroed]
#define OFF_INVCNT 5120       // float[100000]
#define OFF_AGG1   405120     // float2[100000]
#define OFF_DECW   1205120    // dec MFMA tables: 2112 dwords = 8448B
#define OFF_BUCKET 1214848    // int[782*4608] packed entries s|(dloc<<17) (14.4 MB)
#define OFF_PENC   15629696   // float2[782*3*128] enc partials (2.4 MB)
#define OFF_PCNT   22836608   // int[782*3*128]   count partials (1.2 MB)
#define OFF_PDEC   26440064   // float4[782*3*128] dec partials (4.8 MB)
#define OFF_ENCW   26440064   // enc tables alias pdec head (dead before k_dec writes)

// table layout (dword offsets), identical enc/dec:
//   [0,256)      W1 hi (+bias row: enc k=8, dec k=4)
//   [256,512)    W1 lo (+bias residual row)
//   [512,768)    W2 hi k-tile0   [768,1024)  W2 hi k-tile1
//   [1024,1280)  W2 lo k-tile0   [1280,1536) W2 lo k-tile1
//   [1536,1792)  W3 k-tile0      [1792,2048) W3 k-tile1  (hi only; rows remapped)
//   [2048,2080)  b2 C-frag tab (f32, [hi*16+r])
//   [2080,2112)  b3 tab (remapped rows)

// hi/lo f16 split: part 0 = f16(v), part 1 = f16(v - f16(v)); packs a pair.
static __device__ __forceinline__ uint pk_part(float a, float b, int part) {
    _Float16 ah = (_Float16)a, bh = (_Float16)b;
    if (part) {
        a -= (float)ah; b -= (float)bh;
        ah = (_Float16)a; bh = (_Float16)b;
    }
    return (uint)__builtin_bit_cast(unsigned short, ah) |
           ((uint)__builtin_bit_cast(unsigned short, bh) << 16);
}

// Build all MFMA fragment tables (R8-verified). A[m][k]: m=lane&31, k=8*hi+e.
// L1 bias rides a weight ROW: enc A[m][8]=BN-folded b1, dec A[m][4]=db1.
// W3 rows remapped for split atomics; W3 hi-part only.
__global__ __launch_bounds__(256) void k_prep(const double* __restrict__ stats,
                                              const float* __restrict__ bn_w,
                                              const float* __restrict__ bn_b,
                                              const float* __restrict__ ew1,
                                              const float* __restrict__ eb1,
                                              const float* __restrict__ ew2,
                                              const float* __restrict__ eb2,
                                              const float* __restrict__ ew3,
                                              const float* __restrict__ eb3,
                                              const float* __restrict__ dw1,
                                              const float* __restrict__ db1,
                                              const float* __restrict__ dw2,
                                              const float* __restrict__ db2,
                                              const float* __restrict__ dw3,
                                              const float* __restrict__ db3,
                                              uint* __restrict__ encw,
                                              uint* __restrict__ decw) {
    int t = threadIdx.x;
    int lane = t >> 2, d = t & 3;
    int hi = lane >> 5, m = lane & 31;

    const double inv_n = 1.0 / (double)N_NODES;
    float sc[4], sh[4];
    #pragma unroll
    for (int dd = 0; dd < 4; dd++) {
        double mu = stats[dd] * inv_n;
        double vr = stats[4 + dd] * inv_n - mu * mu;
        float rs = (float)(1.0 / sqrt(vr + (double)EPS));
        sc[dd] = rs * bn_w[dd];
        sh[dd] = bn_b[dd] - (float)mu * sc[dd];
    }
    float b1p = eb1[m];
    #pragma unroll
    for (int dd = 0; dd < 4; dd++) b1p += ew1[dd * 32 + m] * sh[dd];

    int k0 = 8 * hi + 2 * d;
    {   // enc W1 hi+lo (BN-folded weights) + bias row k=8
        float v0 = (k0 < 8) ? ew1[k0 * 32 + m] * sc[k0 & 3]
                            : (k0 == 8 ? b1p : 0.f);
        float v1 = (k0 + 1 < 8) ? ew1[(k0 + 1) * 32 + m] * sc[(k0 + 1) & 3] : 0.f;
        encw[t] = pk_part(v0, v1, 0);
        encw[256 + t] = pk_part(v0, v1, 1);
    }
    {   // dec W1 hi+lo + bias row k=4
        float v0 = (k0 < 4) ? dw1[k0 * 32 + m] : (k0 == 4 ? db1[m] : 0.f);
        float v1 = (k0 + 1 < 4) ? dw1[(k0 + 1) * 32 + m] : 0.f;
        decw[t] = pk_part(v0, v1, 0);
        decw[256 + t] = pk_part(v0, v1, 1);
    }
    #pragma unroll
    for (int tile = 0; tile < 2; tile++) {   // W2 (K=32, 2 k-tiles), hi+lo
        int k = 16 * tile + k0;
        {
            float a = ew2[k * 32 + m], bb = ew2[(k + 1) * 32 + m];
            encw[512 + tile * 256 + t] = pk_part(a, bb, 0);
            encw[1024 + tile * 256 + t] = pk_part(a, bb, 1);
        }
        {
            float a = dw2[k * 32 + m], bb = dw2[(k + 1) * 32 + m];
            decw[512 + tile * 256 + t] = pk_part(a, bb, 0);
            decw[1024 + tile * 256 + t] = pk_part(a, bb, 1);
        }
        {   // enc W3 (32->2), hi only, rows {0,4}
            float a = 0.f, bb = 0.f;
            if (m == 0 || m == 4) {
                int o = m >> 2;
                a = ew3[k * 2 + o]; bb = ew3[(k + 1) * 2 + o];
            }
            encw[1536 + tile * 256 + t] = pk_part(a, bb, 0);
        }
        {   // dec W3 (32->4), hi only, rows {0,1,4,5}
            float a = 0.f, bb = 0.f;
            if ((m & 3) < 2 && m < 6) {
                int o = (m & 1) + 2 * (m >> 2);
                a = dw3[k * 4 + o]; bb = dw3[(k + 1) * 4 + o];
            }
            decw[1536 + tile * 256 + t] = pk_part(a, bb, 0);
        }
    }
    if (t < 32) {   // bias tabs: index hh*16+r, value bias[row(r,hh)]
        int hh = t >> 4, r = t & 15;
        int row = (r & 3) + 8 * (r >> 2) + 4 * hh;
        ((float*)encw)[2048 + t] = eb2[row];
        ((float*)encw)[2080 + t] = (row == 0) ? eb3[0] : (row == 4) ? eb3[1] : 0.f;
        ((float*)decw)[2048 + t] = db2[row];
        ((float*)decw)[2080 + t] =
            ((row & 3) < 2 && row < 6) ? db3[(row & 1) + 2 * (row >> 2)] : 0.f;
    }
}

// S1 + fused BN stats (R9-verified): each block accumulates its 256-node BN
// slice, then bins its 8192 edges by bucket = dst>>7 into fixed-stride
// regions, 4B packed entries s|(dloc<<17).
__global__ __launch_bounds__(256) void k_s1(const float* __restrict__ x,
                                            double* __restrict__ stats,
                                            const int* __restrict__ ei,
                                            int* __restrict__ bcnt,
                                            int* __restrict__ bucket_buf) {
    __shared__ int hist[NB];
    __shared__ int base[NB];
    __shared__ int run[NB];
    __shared__ int gbase[NB];
    __shared__ int entries[S1_EPB];
    __shared__ unsigned short bk16[S1_EPB];
    __shared__ int wsum[4];
    __shared__ double smem_bn[4][8];
    int tid = threadIdx.x;

    {   // ---- BN stats slice ----
        int i = blockIdx.x * 256 + tid;
        float4 v = make_float4(0.f, 0.f, 0.f, 0.f);
        if (i < N_NODES) v = ((const float4*)x)[i];
        double a[8];
        a[0] = v.x; a[1] = v.y; a[2] = v.z; a[3] = v.w;
        a[4] = (double)v.x * v.x; a[5] = (double)v.y * v.y;
        a[6] = (double)v.z * v.z; a[7] = (double)v.w * v.w;
        #pragma unroll
        for (int off = 32; off > 0; off >>= 1) {
            #pragma unroll
            for (int j = 0; j < 8; j++) a[j] += __shfl_down(a[j], off);
        }
        int wave = tid >> 6, lane = tid & 63;
        if (lane == 0) {
            #pragma unroll
            for (int j = 0; j < 8; j++) smem_bn[wave][j] = a[j];
        }
        __syncthreads();
        if (tid == 0) {
            #pragma unroll
            for (int j = 0; j < 8; j++) {
                double t2 = smem_bn[0][j] + smem_bn[1][j] + smem_bn[2][j] + smem_bn[3][j];
                atomicAdd(&stats[j], t2);
            }
        }
    }

    // ---- edge binning ----
    int e0 = blockIdx.x * S1_EPB;
    for (int i = tid; i < NB; i += 256) hist[i] = 0;
    __syncthreads();
    #pragma unroll
    for (int k = 0; k < S1_EPB / 256; k++) {
        int e = e0 + k * 256 + tid;
        if (e < N_EDGES) atomicAdd(&hist[ei[N_EDGES + e] >> 7], 1);
    }
    __syncthreads();
    int t4 = tid * 4;
    int h0 = (t4 + 0 < NB) ? hist[t4 + 0] : 0;
    int h1 = (t4 + 1 < NB) ? hist[t4 + 1] : 0;
    int h2 = (t4 + 2 < NB) ? hist[t4 + 2] : 0;
    int h3 = (t4 + 3 < NB) ? hist[t4 + 3] : 0;
    int tsum = h0 + h1 + h2 + h3;
    int lane = tid & 63, wv = tid >> 6;
    int xs = tsum;
    #pragma unroll
    for (int off = 1; off < 64; off <<= 1) {
        int u = __shfl_up(xs, off);
        if (lane >= off) xs += u;
    }
    if (lane == 63) wsum[wv] = xs;
    __syncthreads();
    int wo = 0;
    #pragma unroll
    for (int w = 0; w < 4; w++) if (w < wv) wo += wsum[w];
    int texcl = wo + xs - tsum;
    if (t4 + 0 < NB) base[t4 + 0] = texcl;
    if (t4 + 1 < NB) base[t4 + 1] = texcl + h0;
    if (t4 + 2 < NB) base[t4 + 2] = texcl + h0 + h1;
    if (t4 + 3 < NB) base[t4 + 3] = texcl + h0 + h1 + h2;
    __syncthreads();
    for (int i = tid; i < NB; i += 256) {
        int h = hist[i];
        gbase[i] = i * BSTRIDE + (h ? atomicAdd(&bcnt[i], h) : 0);
        run[i] = base[i];
    }
    __syncthreads();
    #pragma unroll
    for (int k = 0; k < S1_EPB / 256; k++) {
        int e = e0 + k * 256 + tid;
        if (e < N_EDGES) {
            int s = ei[e];
            int d = ei[N_EDGES + e];
            int b = d >> 7;
            int r = atomicAdd(&run[b], 1);   // LDS
            entries[r] = s | ((d & 127) << 17);
            bk16[r] = (unsigned short)b;
        }
    }
    __syncthreads();
    int nloc = min(S1_EPB, N_EDGES - e0);
    for (int idx = tid; idx < nloc; idx += 256) {
        int b = bk16[idx];
        bucket_buf[gbase[b] + (idx - base[b])] = entries[idx];
    }
}

// Fused (BN-folded) encoder 8->32->32->2, all three layers on the matrix pipe.
// R8-verified (best measured enc/dec at NSUB=3): 3-window pipeline, L1 = 2
// MFMAs with bias-in-row (no b1f fragment), gathers on hi=0 lanes only,
// launch_bounds(256,4).
__global__ __launch_bounds__(256, 4) void k_enc_partial(const float* __restrict__ x,
                                                        const int* __restrict__ bucket_buf,
                                                        const int* __restrict__ bcnt,
                                                        float2* __restrict__ penc,
                                                        int* __restrict__ pcnt,
                                                        const uint* __restrict__ encw) {
    __shared__ float4 xs[128];
    __shared__ float acc0[128], acc1[128];
    __shared__ int lc[128];
    int b = blockIdx.x, sub = blockIdx.y, tid = threadIdx.x;
    int lane = tid & 63, hi = lane >> 5, col = lane & 31, wv = tid >> 6;
    int cb = bcnt[b];
    int node0 = b << 7;

    if (tid < 128) {
        acc0[tid] = 0.f; acc1[tid] = 0.f; lc[tid] = 0;
        int n = node0 + tid;
        if (n >= N_NODES) n = 0;
        xs[tid] = ((const float4*)x)[n];   // raw x (BN folded into weights)
    }
    __syncthreads();

    const u32x4* W4 = (const u32x4*)encw;
    u32x4 w1h  = W4[lane],       w1l  = W4[64 + lane];
    u32x4 w2h0 = W4[128 + lane], w2h1 = W4[192 + lane];
    u32x4 w2l0 = W4[256 + lane], w2l1 = W4[320 + lane];
    u32x4 w30  = W4[384 + lane], w31  = W4[448 + lane];
    const float* tf = (const float*)encw;
    f32x16 b2f;
    {
        const float4* p2 = (const float4*)(tf + 2048 + hi * 16);
        #pragma unroll
        for (int q = 0; q < 4; q++) {
            float4 c = p2[q];
            b2f[4 * q] = c.x; b2f[4 * q + 1] = c.y; b2f[4 * q + 2] = c.z; b2f[4 * q + 3] = c.w;
        }
    }
    float bc0 = tf[2080 + hi * 16] - b2f[0];
    float* accH = hi ? acc1 : acc0;
    uint z = 0;

    int wb0 = sub * 1536 + wv * 128;
    if (wb0 < cb) {
        const int4* BB = (const int4*)&bucket_buf[b * BSTRIDE];
        int i0 = (wb0 >> 2) + col;
        int4 qa = BB[i0];
        int4 qb = BB[i0 + 128];
        int4 qc = BB[i0 + 256];
        bool act1 = (wb0 + 512) < cb;
        bool act2 = (wb0 + 1024) < cb;

        auto enc_win = [&](const int* ia, const float4* xg, int wb) {
            #pragma unroll
            for (int j = 0; j < 4; j++) {
                u32x4 xf;
                if (hi == 0) {
                    float4 xi = xs[ia[j]];
                    xf.x = pkh(xi.x, xi.y);
                    xf.y = pkh(xi.z, xi.w);
                    xf.z = pkh(xg[j].x - xi.x, xg[j].y - xi.y);
                    xf.w = pkh(xg[j].z - xi.z, xg[j].w - xi.w);
                } else {
                    xf.x = 0x00003C00u;   // k=8 bias row == 1.0
                    xf.y = 0u; xf.z = 0u; xf.w = 0u;
                }
                f32x16 c = {};
                c = MFMA(w1h, xf, c);
                c = MFMA(w1l, xf, c);
                u32x4 f0, f1;
                repack(c, f0, f1, z);
                f32x16 c2 = MFMA(w2h0, f0, b2f);
                c2 = MFMA(w2h1, f1, c2);
                c2 = MFMA(w2l0, f0, c2);
                c2 = MFMA(w2l1, f1, c2);
                u32x4 e0, e1;
                repack(c2, e0, e1, z);
                f32x16 c3 = MFMA(w30, e0, b2f);   // init garbage cancelled by bc0
                c3 = MFMA(w31, e1, c3);
                float o = fmaxf(c3[0] + bc0, 0.f);
                if ((wb + col * 4 + j) < cb) {
                    atomicAdd(&accH[ia[j]], o);
                    if (hi == 0) atomicAdd(&lc[ia[j]], 1);
                }
            }
        };

        int s0[4], s1[4], s2[4], ia0[4], ia1[4], ia2[4];
        float4 xg0[4], xg1[4], xg2[4];
        decode4(qa, s0, ia0);
        if (hi == 0) {
            #pragma unroll
            for (int k = 0; k < 4; k++) xg0[k] = ((const float4*)x)[s0[k]];
        }
        if (act1) {
            decode4(qb, s1, ia1);
            if (hi == 0) {
                #pragma unroll
                for (int k = 0; k < 4; k++) xg1[k] = ((const float4*)x)[s1[k]];
            }
        }
        enc_win(ia0, xg0, wb0);
        if (act2) {
            decode4(qc, s2, ia2);
            if (hi == 0) {
                #pragma unroll
                for (int k = 0; k < 4; k++) xg2[k] = ((const float4*)x)[s2[k]];
            }
        }
        if (act1) enc_win(ia1, xg1, wb0 + 512);
        if (act2) enc_win(ia2, xg2, wb0 + 1024);
    }
    __syncthreads();
    if (tid < 128) {
        int pb = b * NSUB + sub;
        penc[pb * 128 + tid] = make_float2(acc0[tid], acc1[tid]);
        pcnt[pb * 128 + tid] = lc[tid];
    }
}

// sum NSUB chunk-partials per node -> agg1 (mean) + invcnt
__global__ __launch_bounds__(256) void k_reduce_enc_p(const float2* __restrict__ penc,
                                                      const int* __restrict__ pcnt,
                                                      float2* __restrict__ agg1,
                                                      float* __restrict__ invcnt) {
    int i = blockIdx.x * 256 + threadIdx.x;
    if (i >= N_NODES) return;
    int b = i >> 7, l = i & 127;
    float a0 = 0.f, a1 = 0.f;
    int c = 0;
    #pragma unroll
    for (int sub = 0; sub < NSUB; sub++) {
        int idx = (b * NSUB + sub) * 128 + l;
        float2 p = penc[idx];
        a0 += p.x; a1 += p.y;
        c += pcnt[idx];
    }
    float ic = 1.0f / (float)(c > 1 ? c : 1);
    invcnt[i] = ic;
    agg1[i] = make_float2(a0 * ic, a1 * ic);
}

// Fused decoder 4->32->32->4 (R8-verified): L1 = 2 MFMAs, bias row k=4.
// Split atomics: hi=0 -> out0,1; hi=1 -> out2,3 (W3 rows 0,1,4,5).
__global__ __launch_bounds__(256, 4) void k_dec_partial(const float2* __restrict__ henc,
                                                        const int* __restrict__ bucket_buf,
                                                        const int* __restrict__ bcnt,
                                                        float4* __restrict__ pdec,
                                                        const uint* __restrict__ decw) {
    __shared__ float2 hld[128];
    __shared__ float a0s[128], a1s[128], a2s[128], a3s[128];
    int b = blockIdx.x, sub = blockIdx.y, tid = threadIdx.x;
    int lane = tid & 63, hi = lane >> 5, col = lane & 31, wv = tid >> 6;
    int cb = bcnt[b];
    int node0 = b << 7;

    if (tid < 128) {
        a0s[tid] = 0.f; a1s[tid] = 0.f; a2s[tid] = 0.f; a3s[tid] = 0.f;
        int n = node0 + tid;
        if (n >= N_NODES) n = 0;
        hld[tid] = henc[n];
    }
    __syncthreads();

    const u32x4* W4 = (const u32x4*)decw;
    u32x4 w1h  = W4[lane],       w1l  = W4[64 + lane];
    u32x4 v2h0 = W4[128 + lane], v2h1 = W4[192 + lane];
    u32x4 v2l0 = W4[256 + lane], v2l1 = W4[320 + lane];
    u32x4 w30  = W4[384 + lane], w31  = W4[448 + lane];
    const float* tf = (const float*)decw;
    f32x16 b2f;
    {
        const float4* p2 = (const float4*)(tf + 2048 + hi * 16);
        #pragma unroll
        for (int q = 0; q < 4; q++) {
            float4 c = p2[q];
            b2f[4 * q] = c.x; b2f[4 * q + 1] = c.y; b2f[4 * q + 2] = c.z; b2f[4 * q + 3] = c.w;
        }
    }
    float bc0 = tf[2080 + hi * 16 + 0] - b2f[0];
    float bc1 = tf[2080 + hi * 16 + 1] - b2f[1];
    float* accA = hi ? a2s : a0s;
    float* accB = hi ? a3s : a1s;
    uint z = 0;

    int wb0 = sub * 1536 + wv * 128;
    if (wb0 < cb) {
        const int4* BB = (const int4*)&bucket_buf[b * BSTRIDE];
        int i0 = (wb0 >> 2) + col;
        int4 qa = BB[i0];
        int4 qb = BB[i0 + 128];
        int4 qc = BB[i0 + 256];
        bool act1 = (wb0 + 512) < cb;
        bool act2 = (wb0 + 1024) < cb;

        auto dec_win = [&](const int* ia, const float2* hj, int wb) {
            #pragma unroll
            for (int j = 0; j < 4; j++) {
                u32x4 xf;
                if (hi == 0) {
                    float2 h2 = hld[ia[j]];
                    xf.x = pkh(h2.x, h2.y);
                    xf.y = pkh(hj[j].x - h2.x, hj[j].y - h2.y);
                    xf.z = 0x00003C00u;   // k=4 bias row == 1.0
                    xf.w = 0u;
                } else {
                    xf.x = 0u; xf.y = 0u; xf.z = 0u; xf.w = 0u;
                }
                f32x16 c = {};
                c = MFMA(w1h, xf, c);
                c = MFMA(w1l, xf, c);
                u32x4 f0, f1;
                repack(c, f0, f1, z);
                f32x16 c2 = MFMA(v2h0, f0, b2f);
                c2 = MFMA(v2h1, f1, c2);
                c2 = MFMA(v2l0, f0, c2);
                c2 = MFMA(v2l1, f1, c2);
                u32x4 e0, e1;
                repack(c2, e0, e1, z);
                f32x16 c3 = MFMA(w30, e0, b2f);
                c3 = MFMA(w31, e1, c3);
                float o0 = c3[0] + bc0;
                float o1 = c3[1] + bc1;
                if ((wb + col * 4 + j) < cb) {
                    atomicAdd(&accA[ia[j]], o0);
                    atomicAdd(&accB[ia[j]], o1);
                }
            }
        };

        int s0[4], s1[4], s2[4], ia0[4], ia1[4], ia2[4];
        float2 hg0[4], hg1[4], hg2[4];
        decode4(qa, s0, ia0);
        if (hi == 0) {
            #pragma unroll
            for (int k = 0; k < 4; k++) hg0[k] = henc[s0[k]];
        }
        if (act1) {
            decode4(qb, s1, ia1);
            if (hi == 0) {
                #pragma unroll
                for (int k = 0; k < 4; k++) hg1[k] = henc[s1[k]];
            }
        }
        dec_win(ia0, hg0, wb0);
        if (act2) {
            decode4(qc, s2, ia2);
            if (hi == 0) {
                #pragma unroll
                for (int k = 0; k < 4; k++) hg2[k] = henc[s2[k]];
            }
        }
        if (act1) dec_win(ia1, hg1, wb0 + 512);
        if (act2) dec_win(ia2, hg2, wb0 + 1024);
    }
    __syncthreads();
    if (tid < 128) {
        int pb = b * NSUB + sub;
        pdec[pb * 128 + tid] = make_float4(a0s[tid], a1s[tid], a2s[tid], a3s[tid]);
    }
}

// sum NSUB chunk-partials per node -> final output (mean)
__global__ __launch_bounds__(256) void k_reduce_dec_p(const float4* __restrict__ pdec,
                                                      const float* __restrict__ invcnt,
                                                      float4* __restrict__ out) {
    int i = blockIdx.x * 256 + threadIdx.x;
    if (i >= N_NODES) return;
    int b = i >> 7, l = i & 127;
    float a0 = 0.f, a1 = 0.f, a2 = 0.f, a3 = 0.f;
    #pragma unroll
    for (int sub = 0; sub < NSUB; sub++) {
        float4 p = pdec[(b * NSUB + sub) * 128 + l];
        a0 += p.x; a1 += p.y; a2 += p.z; a3 += p.w;
    }
    float ic = invcnt[i];
    out[i] = make_float4(a0 * ic, a1 * ic, a2 * ic, a3 * ic);
}

extern "C" void kernel_launch(void* const* d_in, const int* in_sizes, int n_in,
                              void* d_out, int out_size, void* d_ws, size_t ws_size,
                              hipStream_t stream) {
    const float* x    = (const float*)d_in[0];
    const int*   ei   = (const int*)d_in[1];
    const float* bn_w = (const float*)d_in[2];
    const float* bn_b = (const float*)d_in[3];
    const float* ew1  = (const float*)d_in[4];
    const float* eb1  = (const float*)d_in[5];
    const float* ew2  = (const float*)d_in[6];
    const float* eb2  = (const float*)d_in[7];
    const float* ew3  = (const float*)d_in[8];
    const float* eb3  = (const float*)d_in[9];
    const float* dw1  = (const float*)d_in[10];
    const float* db1  = (const float*)d_in[11];
    const float* dw2  = (const float*)d_in[12];
    const float* db2  = (const float*)d_in[13];
    const float* dw3  = (const float*)d_in[14];
    const float* db3  = (const float*)d_in[15];

    char* ws = (char*)d_ws;
    double* stats      = (double*)(ws + OFF_STATS);
    int*    bcnt       = (int*)(ws + OFF_BCNT);
    float*  invcnt     = (float*)(ws + OFF_INVCNT);
    float2* agg1       = (float2*)(ws + OFF_AGG1);
    uint*   decw       = (uint*)(ws + OFF_DECW);
    int*    bucket_buf = (int*)(ws + OFF_BUCKET);
    float2* penc       = (float2*)(ws + OFF_PENC);
    int*    pcnt       = (int*)(ws + OFF_PCNT);
    float4* pdec       = (float4*)(ws + OFF_PDEC);
    uint*   encw       = (uint*)(ws + OFF_ENCW);
    float4* out        = (float4*)d_out;

    // zero: stats + bucket counts, contiguous [0, 5120)
    hipMemsetAsync(ws, 0, 5120, stream);

    k_s1<<<S1_BLOCKS, 256, 0, stream>>>(x, stats, ei, bcnt, bucket_buf);
    k_prep<<<1, 256, 0, stream>>>(stats, bn_w, bn_b, ew1, eb1, ew2, eb2, ew3, eb3,
                                  dw1, db1, dw2, db2, dw3, db3, encw, decw);
    k_enc_partial<<<dim3(NB, NSUB), 256, 0, stream>>>(x, bucket_buf, bcnt,
                                                      penc, pcnt, encw);
    k_reduce_enc_p<<<NODE_BLOCKS, 256, 0, stream>>>(penc, pcnt, agg1, invcnt);
    k_dec_partial<<<dim3(NB, NSUB), 256, 0, stream>>>(agg1, bucket_buf, bcnt, pdec, decw);
    k_reduce_dec_p<<<NODE_BLOCKS, 256, 0, stream>>>(pdec, invcnt, out);
}

// Round 11
// 289.532 us; speedup vs baseline: 1.0736x; 1.0168x over previous
//
#include <hip/hip_runtime.h>

#define N_NODES 100000
#define N_EDGES 3200000
#define EPS 1e-5f
#define NODE_BLOCKS 391   // ceil(100000/256)
#define NB 782            // buckets of 128 nodes (dst >> 7)
#define BSTRIDE 4608      // fixed bucket region: mean 4096 + 8 sigma
#define NSUB 3            // chunks of 1536 slots per bucket (3*1536 = 4608)
#define S1_EPB 8192
#define S1_BLOCKS 391

typedef unsigned int uint;
typedef uint u32x4 __attribute__((ext_vector_type(4)));
typedef _Float16 f16x8 __attribute__((ext_vector_type(8)));
typedef float f32x16 __attribute__((ext_vector_type(16)));

static __device__ __forceinline__ f16x8 as_h8(u32x4 u) { return __builtin_bit_cast(f16x8, u); }
static __device__ __forceinline__ uint pkh(float a, float b) {
    return __builtin_bit_cast(uint, __builtin_amdgcn_cvt_pkrtz(a, b));
}
// v_permlane32_swap_b32: a' = [a.lo32 | b.lo32], b' = [a.hi32 | b.hi32]
// volatile + this exact usage is the R1-R3/R7/R8/R10 verified pattern. Do NOT
// touch: R5/R6 experiments around this instruction failed verification twice.
static __device__ __forceinline__ void swap32(uint& a, uint& b) {
    asm volatile("v_permlane32_swap_b32 %0, %1" : "+v"(a), "+v"(b));
}
// packed f16 relu: max(x, 0) on both halves. rtz-then-relu == relu-then-rtz.
static __device__ __forceinline__ uint prelu(uint u, uint z) {
    uint r;
    asm("v_pk_max_f16 %0, %1, %2" : "=v"(r) : "v"(u), "v"(z));
    return r;
}

#define MFMA(A, B, C) __builtin_amdgcn_mfma_f32_32x32x16_f16(as_h8(A), as_h8(B), (C), 0, 0, 0)

// Repack MFMA C (32 rows x 32 edge-cols, row=(r&3)+8*(r>>2)+4*hi) into the two
// B-fragments for the next K=32 MFMA pair, applying relu in packed f16.
// Verified pattern (R1-R3,R7,R8,R10): pkh pairs + 4x permlane32_swap.
static __device__ __forceinline__ void repack(const f32x16& c, u32x4& f0, u32x4& f1, uint z) {
    uint p0 = prelu(pkh(c[0], c[1]), z),   p1 = prelu(pkh(c[2], c[3]), z);
    uint q0 = prelu(pkh(c[4], c[5]), z),   q1 = prelu(pkh(c[6], c[7]), z);
    uint p2 = prelu(pkh(c[8], c[9]), z),   p3 = prelu(pkh(c[10], c[11]), z);
    uint q2 = prelu(pkh(c[12], c[13]), z), q3 = prelu(pkh(c[14], c[15]), z);
    swap32(p0, q0); swap32(p1, q1);
    swap32(p2, q2); swap32(p3, q3);
    f0.x = p0; f0.y = p1; f0.z = q0; f0.w = q1;
    f1.x = p2; f1.y = p3; f1.z = q2; f1.w = q3;
}

static __device__ __forceinline__ void decode4(const int4& q, int* ss, int* ia) {
    int e0 = q.x, e1 = q.y, e2 = q.z, e3 = q.w;
    ss[0] = e0 & 0x1FFFF; ia[0] = (e0 >> 17) & 127;
    ss[1] = e1 & 0x1FFFF; ia[1] = (e1 >> 17) & 127;
    ss[2] = e2 & 0x1FFFF; ia[2] = (e2 >> 17) & 127;
    ss[3] = e3 & 0x1FFFF; ia[3] = (e3 >> 17) & 127;
    #pragma unroll
    for (int k = 0; k < 4; k++)
        if (ss[k] >= N_NODES) ss[k] = 0;   // slots >= cb hold stale garbage
}

// ---- workspace layout (bytes) ----
#define OFF_STATS  0          // 8 doubles (bn sums)          [zeroed]
#define OFF_BCNT   1024       // int[782] bucket counts       [zeroed]
#define OFF_INVCNT 5120       // float[100000]
#define OFF_AGG1   405120     // float2[100000]
#define OFF_DECW   1205120    // dec MFMA tables: 2112 dwords = 8448B
#define OFF_BUCKET 1214848    // int[782*4608] packed entries s|(dloc<<17) (14.4 MB)
#define OFF_PENC   15629696   // float2[782*3*128] enc partials (2.4 MB)
#define OFF_PCNT   22836608   // int[782*3*128]   count partials (1.2 MB)
#define OFF_PDEC   26440064   // float4[782*3*128] dec partials (4.8 MB)
#define OFF_ENCW   26440064   // enc tables alias pdec head (dead before k_dec writes)

// table layout (dword offsets), identical enc/dec:
//   [0,256)      W1 hi (+bias row: enc k=8, dec k=4)
//   [256,512)    W1 lo (+bias residual row)
//   [512,768)    W2 hi k-tile0   [768,1024)  W2 hi k-tile1
//   [1024,1280)  W2 lo k-tile0   [1280,1536) W2 lo k-tile1
//   [1536,1792)  W3 k-tile0      [1792,2048) W3 k-tile1  (hi only; rows remapped)
//   [2048,2080)  b2 C-frag tab (f32, [hi*16+r])
//   [2080,2112)  b3 tab (remapped rows)

// hi/lo f16 split: part 0 = f16(v), part 1 = f16(v - f16(v)); packs a pair.
static __device__ __forceinline__ uint pk_part(float a, float b, int part) {
    _Float16 ah = (_Float16)a, bh = (_Float16)b;
    if (part) {
        a -= (float)ah; b -= (float)bh;
        ah = (_Float16)a; bh = (_Float16)b;
    }
    return (uint)__builtin_bit_cast(unsigned short, ah) |
           ((uint)__builtin_bit_cast(unsigned short, bh) << 16);
}

// Build all MFMA fragment tables (R8/R10-verified). A[m][k]: m=lane&31, k=8*hi+e.
// L1 bias rides a weight ROW: enc A[m][8]=BN-folded b1, dec A[m][4]=db1.
// W3 rows remapped for split atomics; W3 hi-part only.
__global__ __launch_bounds__(256) void k_prep(const double* __restrict__ stats,
                                              const float* __restrict__ bn_w,
                                              const float* __restrict__ bn_b,
                                              const float* __restrict__ ew1,
                                              const float* __restrict__ eb1,
                                              const float* __restrict__ ew2,
                                              const float* __restrict__ eb2,
                                              const float* __restrict__ ew3,
                                              const float* __restrict__ eb3,
                                              const float* __restrict__ dw1,
                                              const float* __restrict__ db1,
                                              const float* __restrict__ dw2,
                                              const float* __restrict__ db2,
                                              const float* __restrict__ dw3,
                                              const float* __restrict__ db3,
                                              uint* __restrict__ encw,
                                              uint* __restrict__ decw) {
    int t = threadIdx.x;
    int lane = t >> 2, d = t & 3;
    int hi = lane >> 5, m = lane & 31;

    const double inv_n = 1.0 / (double)N_NODES;
    float sc[4], sh[4];
    #pragma unroll
    for (int dd = 0; dd < 4; dd++) {
        double mu = stats[dd] * inv_n;
        double vr = stats[4 + dd] * inv_n - mu * mu;
        float rs = (float)(1.0 / sqrt(vr + (double)EPS));
        sc[dd] = rs * bn_w[dd];
        sh[dd] = bn_b[dd] - (float)mu * sc[dd];
    }
    float b1p = eb1[m];
    #pragma unroll
    for (int dd = 0; dd < 4; dd++) b1p += ew1[dd * 32 + m] * sh[dd];

    int k0 = 8 * hi + 2 * d;
    {   // enc W1 hi+lo (BN-folded weights) + bias row k=8
        float v0 = (k0 < 8) ? ew1[k0 * 32 + m] * sc[k0 & 3]
                            : (k0 == 8 ? b1p : 0.f);
        float v1 = (k0 + 1 < 8) ? ew1[(k0 + 1) * 32 + m] * sc[(k0 + 1) & 3] : 0.f;
        encw[t] = pk_part(v0, v1, 0);
        encw[256 + t] = pk_part(v0, v1, 1);
    }
    {   // dec W1 hi+lo + bias row k=4
        float v0 = (k0 < 4) ? dw1[k0 * 32 + m] : (k0 == 4 ? db1[m] : 0.f);
        float v1 = (k0 + 1 < 4) ? dw1[(k0 + 1) * 32 + m] : 0.f;
        decw[t] = pk_part(v0, v1, 0);
        decw[256 + t] = pk_part(v0, v1, 1);
    }
    #pragma unroll
    for (int tile = 0; tile < 2; tile++) {   // W2 (K=32, 2 k-tiles), hi+lo
        int k = 16 * tile + k0;
        {
            float a = ew2[k * 32 + m], bb = ew2[(k + 1) * 32 + m];
            encw[512 + tile * 256 + t] = pk_part(a, bb, 0);
            encw[1024 + tile * 256 + t] = pk_part(a, bb, 1);
        }
        {
            float a = dw2[k * 32 + m], bb = dw2[(k + 1) * 32 + m];
            decw[512 + tile * 256 + t] = pk_part(a, bb, 0);
            decw[1024 + tile * 256 + t] = pk_part(a, bb, 1);
        }
        {   // enc W3 (32->2), hi only, rows {0,4}
            float a = 0.f, bb = 0.f;
            if (m == 0 || m == 4) {
                int o = m >> 2;
                a = ew3[k * 2 + o]; bb = ew3[(k + 1) * 2 + o];
            }
            encw[1536 + tile * 256 + t] = pk_part(a, bb, 0);
        }
        {   // dec W3 (32->4), hi only, rows {0,1,4,5}
            float a = 0.f, bb = 0.f;
            if ((m & 3) < 2 && m < 6) {
                int o = (m & 1) + 2 * (m >> 2);
                a = dw3[k * 4 + o]; bb = dw3[(k + 1) * 4 + o];
            }
            decw[1536 + tile * 256 + t] = pk_part(a, bb, 0);
        }
    }
    if (t < 32) {   // bias tabs: index hh*16+r, value bias[row(r,hh)]
        int hh = t >> 4, r = t & 15;
        int row = (r & 3) + 8 * (r >> 2) + 4 * hh;
        ((float*)encw)[2048 + t] = eb2[row];
        ((float*)encw)[2080 + t] = (row == 0) ? eb3[0] : (row == 4) ? eb3[1] : 0.f;
        ((float*)decw)[2048 + t] = db2[row];
        ((float*)decw)[2080 + t] =
            ((row & 3) < 2 && row < 6) ? db3[(row & 1) + 2 * (row >> 2)] : 0.f;
    }
}

// S1 + fused BN stats. R11: 512 threads/block (was 256) — same LDS (61.5KB,
// 2 blocks/CU) but 16 waves/CU instead of 8 and half the serial rounds per
// phase. R10 counters showed s1 latency-bound at 13.5% occupancy with every
// pipe <6% busy; this doubles TLP without adding per-block bucket overhead
// (R8's EPB-split regression).
__global__ __launch_bounds__(512) void k_s1(const float* __restrict__ x,
                                            double* __restrict__ stats,
                                            const int* __restrict__ ei,
                                            int* __restrict__ bcnt,
                                            int* __restrict__ bucket_buf) {
    __shared__ int hist[NB];
    __shared__ int base[NB];
    __shared__ int run[NB];
    __shared__ int gbase[NB];
    __shared__ int entries[S1_EPB];
    __shared__ unsigned short bk16[S1_EPB];
    __shared__ int wsum[8];
    __shared__ double smem_bn[8][8];
    int tid = threadIdx.x;

    {   // ---- BN stats slice (512 nodes/block, 391 blocks covers 100000) ----
        int i = blockIdx.x * 512 + tid;
        float4 v = make_float4(0.f, 0.f, 0.f, 0.f);
        if (i < N_NODES) v = ((const float4*)x)[i];
        double a[8];
        a[0] = v.x; a[1] = v.y; a[2] = v.z; a[3] = v.w;
        a[4] = (double)v.x * v.x; a[5] = (double)v.y * v.y;
        a[6] = (double)v.z * v.z; a[7] = (double)v.w * v.w;
        #pragma unroll
        for (int off = 32; off > 0; off >>= 1) {
            #pragma unroll
            for (int j = 0; j < 8; j++) a[j] += __shfl_down(a[j], off);
        }
        int wave = tid >> 6, lane = tid & 63;
        if (lane == 0) {
            #pragma unroll
            for (int j = 0; j < 8; j++) smem_bn[wave][j] = a[j];
        }
        __syncthreads();
        if (tid == 0) {
            #pragma unroll
            for (int j = 0; j < 8; j++) {
                double t2 = 0.0;
                #pragma unroll
                for (int w = 0; w < 8; w++) t2 += smem_bn[w][j];
                atomicAdd(&stats[j], t2);
            }
        }
    }

    // ---- edge binning ----
    int e0 = blockIdx.x * S1_EPB;
    for (int i = tid; i < NB; i += 512) hist[i] = 0;
    __syncthreads();
    #pragma unroll
    for (int k = 0; k < S1_EPB / 512; k++) {
        int e = e0 + k * 512 + tid;
        if (e < N_EDGES) atomicAdd(&hist[ei[N_EDGES + e] >> 7], 1);
    }
    __syncthreads();
    int t4 = tid * 4;
    int h0 = (t4 + 0 < NB) ? hist[t4 + 0] : 0;
    int h1 = (t4 + 1 < NB) ? hist[t4 + 1] : 0;
    int h2 = (t4 + 2 < NB) ? hist[t4 + 2] : 0;
    int h3 = (t4 + 3 < NB) ? hist[t4 + 3] : 0;
    int tsum = h0 + h1 + h2 + h3;
    int lane = tid & 63, wv = tid >> 6;
    int xs = tsum;
    #pragma unroll
    for (int off = 1; off < 64; off <<= 1) {
        int u = __shfl_up(xs, off);
        if (lane >= off) xs += u;
    }
    if (lane == 63) wsum[wv] = xs;
    __syncthreads();
    int wo = 0;
    #pragma unroll
    for (int w = 0; w < 8; w++) if (w < wv) wo += wsum[w];
    int texcl = wo + xs - tsum;
    if (t4 + 0 < NB) base[t4 + 0] = texcl;
    if (t4 + 1 < NB) base[t4 + 1] = texcl + h0;
    if (t4 + 2 < NB) base[t4 + 2] = texcl + h0 + h1;
    if (t4 + 3 < NB) base[t4 + 3] = texcl + h0 + h1 + h2;
    __syncthreads();
    for (int i = tid; i < NB; i += 512) {
        int h = hist[i];
        gbase[i] = i * BSTRIDE + (h ? atomicAdd(&bcnt[i], h) : 0);
        run[i] = base[i];
    }
    __syncthreads();
    #pragma unroll
    for (int k = 0; k < S1_EPB / 512; k++) {
        int e = e0 + k * 512 + tid;
        if (e < N_EDGES) {
            int s = ei[e];
            int d = ei[N_EDGES + e];
            int b = d >> 7;
            int r = atomicAdd(&run[b], 1);   // LDS
            entries[r] = s | ((d & 127) << 17);
            bk16[r] = (unsigned short)b;
        }
    }
    __syncthreads();
    int nloc = min(S1_EPB, N_EDGES - e0);
    for (int idx = tid; idx < nloc; idx += 512) {
        int b = bk16[idx];
        bucket_buf[gbase[b] + (idx - base[b])] = entries[idx];
    }
}

// Fused (BN-folded) encoder 8->32->32->2, all three layers on the matrix pipe.
// R8/R10-verified (best measured enc/dec at NSUB=3): 3-window pipeline, L1 =
// 2 MFMAs with bias-in-row, gathers on hi=0 lanes only, launch_bounds(256,4).
__global__ __launch_bounds__(256, 4) void k_enc_partial(const float* __restrict__ x,
                                                        const int* __restrict__ bucket_buf,
                                                        const int* __restrict__ bcnt,
                                                        float2* __restrict__ penc,
                                                        int* __restrict__ pcnt,
                                                        const uint* __restrict__ encw) {
    __shared__ float4 xs[128];
    __shared__ float acc0[128], acc1[128];
    __shared__ int lc[128];
    int b = blockIdx.x, sub = blockIdx.y, tid = threadIdx.x;
    int lane = tid & 63, hi = lane >> 5, col = lane & 31, wv = tid >> 6;
    int cb = bcnt[b];
    int node0 = b << 7;

    if (tid < 128) {
        acc0[tid] = 0.f; acc1[tid] = 0.f; lc[tid] = 0;
        int n = node0 + tid;
        if (n >= N_NODES) n = 0;
        xs[tid] = ((const float4*)x)[n];   // raw x (BN folded into weights)
    }
    __syncthreads();

    const u32x4* W4 = (const u32x4*)encw;
    u32x4 w1h  = W4[lane],       w1l  = W4[64 + lane];
    u32x4 w2h0 = W4[128 + lane], w2h1 = W4[192 + lane];
    u32x4 w2l0 = W4[256 + lane], w2l1 = W4[320 + lane];
    u32x4 w30  = W4[384 + lane], w31  = W4[448 + lane];
    const float* tf = (const float*)encw;
    f32x16 b2f;
    {
        const float4* p2 = (const float4*)(tf + 2048 + hi * 16);
        #pragma unroll
        for (int q = 0; q < 4; q++) {
            float4 c = p2[q];
            b2f[4 * q] = c.x; b2f[4 * q + 1] = c.y; b2f[4 * q + 2] = c.z; b2f[4 * q + 3] = c.w;
        }
    }
    float bc0 = tf[2080 + hi * 16] - b2f[0];
    float* accH = hi ? acc1 : acc0;
    uint z = 0;

    int wb0 = sub * 1536 + wv * 128;
    if (wb0 < cb) {
        const int4* BB = (const int4*)&bucket_buf[b * BSTRIDE];
        int i0 = (wb0 >> 2) + col;
        int4 qa = BB[i0];
        int4 qb = BB[i0 + 128];
        int4 qc = BB[i0 + 256];
        bool act1 = (wb0 + 512) < cb;
        bool act2 = (wb0 + 1024) < cb;

        auto enc_win = [&](const int* ia, const float4* xg, int wb) {
            #pragma unroll
            for (int j = 0; j < 4; j++) {
                u32x4 xf;
                if (hi == 0) {
                    float4 xi = xs[ia[j]];
                    xf.x = pkh(xi.x, xi.y);
                    xf.y = pkh(xi.z, xi.w);
                    xf.z = pkh(xg[j].x - xi.x, xg[j].y - xi.y);
                    xf.w = pkh(xg[j].z - xi.z, xg[j].w - xi.w);
                } else {
                    xf.x = 0x00003C00u;   // k=8 bias row == 1.0
                    xf.y = 0u; xf.z = 0u; xf.w = 0u;
                }
                f32x16 c = {};
                c = MFMA(w1h, xf, c);
                c = MFMA(w1l, xf, c);
                u32x4 f0, f1;
                repack(c, f0, f1, z);
                f32x16 c2 = MFMA(w2h0, f0, b2f);
                c2 = MFMA(w2h1, f1, c2);
                c2 = MFMA(w2l0, f0, c2);
                c2 = MFMA(w2l1, f1, c2);
                u32x4 e0, e1;
                repack(c2, e0, e1, z);
                f32x16 c3 = MFMA(w30, e0, b2f);   // init garbage cancelled by bc0
                c3 = MFMA(w31, e1, c3);
                float o = fmaxf(c3[0] + bc0, 0.f);
                if ((wb + col * 4 + j) < cb) {
                    atomicAdd(&accH[ia[j]], o);
                    if (hi == 0) atomicAdd(&lc[ia[j]], 1);
                }
            }
        };

        int s0[4], s1[4], s2[4], ia0[4], ia1[4], ia2[4];
        float4 xg0[4], xg1[4], xg2[4];
        decode4(qa, s0, ia0);
        if (hi == 0) {
            #pragma unroll
            for (int k = 0; k < 4; k++) xg0[k] = ((const float4*)x)[s0[k]];
        }
        if (act1) {
            decode4(qb, s1, ia1);
            if (hi == 0) {
                #pragma unroll
                for (int k = 0; k < 4; k++) xg1[k] = ((const float4*)x)[s1[k]];
            }
        }
        enc_win(ia0, xg0, wb0);
        if (act2) {
            decode4(qc, s2, ia2);
            if (hi == 0) {
                #pragma unroll
                for (int k = 0; k < 4; k++) xg2[k] = ((const float4*)x)[s2[k]];
            }
        }
        if (act1) enc_win(ia1, xg1, wb0 + 512);
        if (act2) enc_win(ia2, xg2, wb0 + 1024);
    }
    __syncthreads();
    if (tid < 128) {
        int pb = b * NSUB + sub;
        penc[pb * 128 + tid] = make_float2(acc0[tid], acc1[tid]);
        pcnt[pb * 128 + tid] = lc[tid];
    }
}

// sum NSUB chunk-partials per node -> agg1 (mean) + invcnt
__global__ __launch_bounds__(256) void k_reduce_enc_p(const float2* __restrict__ penc,
                                                      const int* __restrict__ pcnt,
                                                      float2* __restrict__ agg1,
                                                      float* __restrict__ invcnt) {
    int i = blockIdx.x * 256 + threadIdx.x;
    if (i >= N_NODES) return;
    int b = i >> 7, l = i & 127;
    float a0 = 0.f, a1 = 0.f;
    int c = 0;
    #pragma unroll
    for (int sub = 0; sub < NSUB; sub++) {
        int idx = (b * NSUB + sub) * 128 + l;
        float2 p = penc[idx];
        a0 += p.x; a1 += p.y;
        c += pcnt[idx];
    }
    float ic = 1.0f / (float)(c > 1 ? c : 1);
    invcnt[i] = ic;
    agg1[i] = make_float2(a0 * ic, a1 * ic);
}

// Fused decoder 4->32->32->4 (R8/R10-verified): L1 = 2 MFMAs, bias row k=4.
// Split atomics: hi=0 -> out0,1; hi=1 -> out2,3 (W3 rows 0,1,4,5).
__global__ __launch_bounds__(256, 4) void k_dec_partial(const float2* __restrict__ henc,
                                                        const int* __restrict__ bucket_buf,
                                                        const int* __restrict__ bcnt,
                                                        float4* __restrict__ pdec,
                                                        const uint* __restrict__ decw) {
    __shared__ float2 hld[128];
    __shared__ float a0s[128], a1s[128], a2s[128], a3s[128];
    int b = blockIdx.x, sub = blockIdx.y, tid = threadIdx.x;
    int lane = tid & 63, hi = lane >> 5, col = lane & 31, wv = tid >> 6;
    int cb = bcnt[b];
    int node0 = b << 7;

    if (tid < 128) {
        a0s[tid] = 0.f; a1s[tid] = 0.f; a2s[tid] = 0.f; a3s[tid] = 0.f;
        int n = node0 + tid;
        if (n >= N_NODES) n = 0;
        hld[tid] = henc[n];
    }
    __syncthreads();

    const u32x4* W4 = (const u32x4*)decw;
    u32x4 w1h  = W4[lane],       w1l  = W4[64 + lane];
    u32x4 v2h0 = W4[128 + lane], v2h1 = W4[192 + lane];
    u32x4 v2l0 = W4[256 + lane], v2l1 = W4[320 + lane];
    u32x4 w30  = W4[384 + lane], w31  = W4[448 + lane];
    const float* tf = (const float*)decw;
    f32x16 b2f;
    {
        const float4* p2 = (const float4*)(tf + 2048 + hi * 16);
        #pragma unroll
        for (int q = 0; q < 4; q++) {
            float4 c = p2[q];
            b2f[4 * q] = c.x; b2f[4 * q + 1] = c.y; b2f[4 * q + 2] = c.z; b2f[4 * q + 3] = c.w;
        }
    }
    float bc0 = tf[2080 + hi * 16 + 0] - b2f[0];
    float bc1 = tf[2080 + hi * 16 + 1] - b2f[1];
    float* accA = hi ? a2s : a0s;
    float* accB = hi ? a3s : a1s;
    uint z = 0;

    int wb0 = sub * 1536 + wv * 128;
    if (wb0 < cb) {
        const int4* BB = (const int4*)&bucket_buf[b * BSTRIDE];
        int i0 = (wb0 >> 2) + col;
        int4 qa = BB[i0];
        int4 qb = BB[i0 + 128];
        int4 qc = BB[i0 + 256];
        bool act1 = (wb0 + 512) < cb;
        bool act2 = (wb0 + 1024) < cb;

        auto dec_win = [&](const int* ia, const float2* hj, int wb) {
            #pragma unroll
            for (int j = 0; j < 4; j++) {
                u32x4 xf;
                if (hi == 0) {
                    float2 h2 = hld[ia[j]];
                    xf.x = pkh(h2.x, h2.y);
                    xf.y = pkh(hj[j].x - h2.x, hj[j].y - h2.y);
                    xf.z = 0x00003C00u;   // k=4 bias row == 1.0
                    xf.w = 0u;
                } else {
                    xf.x = 0u; xf.y = 0u; xf.z = 0u; xf.w = 0u;
                }
                f32x16 c = {};
                c = MFMA(w1h, xf, c);
                c = MFMA(w1l, xf, c);
                u32x4 f0, f1;
                repack(c, f0, f1, z);
                f32x16 c2 = MFMA(v2h0, f0, b2f);
                c2 = MFMA(v2h1, f1, c2);
                c2 = MFMA(v2l0, f0, c2);
                c2 = MFMA(v2l1, f1, c2);
                u32x4 e0, e1;
                repack(c2, e0, e1, z);
                f32x16 c3 = MFMA(w30, e0, b2f);
                c3 = MFMA(w31, e1, c3);
                float o0 = c3[0] + bc0;
                float o1 = c3[1] + bc1;
                if ((wb + col * 4 + j) < cb) {
                    atomicAdd(&accA[ia[j]], o0);
                    atomicAdd(&accB[ia[j]], o1);
                }
            }
        };

        int s0[4], s1[4], s2[4], ia0[4], ia1[4], ia2[4];
        float2 hg0[4], hg1[4], hg2[4];
        decode4(qa, s0, ia0);
        if (hi == 0) {
            #pragma unroll
            for (int k = 0; k < 4; k++) hg0[k] = henc[s0[k]];
        }
        if (act1) {
            decode4(qb, s1, ia1);
            if (hi == 0) {
                #pragma unroll
                for (int k = 0; k < 4; k++) hg1[k] = henc[s1[k]];
            }
        }
        dec_win(ia0, hg0, wb0);
        if (act2) {
            decode4(qc, s2, ia2);
            if (hi == 0) {
                #pragma unroll
                for (int k = 0; k < 4; k++) hg2[k] = henc[s2[k]];
            }
        }
        if (act1) dec_win(ia1, hg1, wb0 + 512);
        if (act2) dec_win(ia2, hg2, wb0 + 1024);
    }
    __syncthreads();
    if (tid < 128) {
        int pb = b * NSUB + sub;
        pdec[pb * 128 + tid] = make_float4(a0s[tid], a1s[tid], a2s[tid], a3s[tid]);
    }
}

// sum NSUB chunk-partials per node -> final output (mean)
__global__ __launch_bounds__(256) void k_reduce_dec_p(const float4* __restrict__ pdec,
                                                      const float* __restrict__ invcnt,
                                                      float4* __restrict__ out) {
    int i = blockIdx.x * 256 + threadIdx.x;
    if (i >= N_NODES) return;
    int b = i >> 7, l = i & 127;
    float a0 = 0.f, a1 = 0.f, a2 = 0.f, a3 = 0.f;
    #pragma unroll
    for (int sub = 0; sub < NSUB; sub++) {
        float4 p = pdec[(b * NSUB + sub) * 128 + l];
        a0 += p.x; a1 += p.y; a2 += p.z; a3 += p.w;
    }
    float ic = invcnt[i];
    out[i] = make_float4(a0 * ic, a1 * ic, a2 * ic, a3 * ic);
}

extern "C" void kernel_launch(void* const* d_in, const int* in_sizes, int n_in,
                              void* d_out, int out_size, void* d_ws, size_t ws_size,
                              hipStream_t stream) {
    const float* x    = (const float*)d_in[0];
    const int*   ei   = (const int*)d_in[1];
    const float* bn_w = (const float*)d_in[2];
    const float* bn_b = (const float*)d_in[3];
    const float* ew1  = (const float*)d_in[4];
    const float* eb1  = (const float*)d_in[5];
    const float* ew2  = (const float*)d_in[6];
    const float* eb2  = (const float*)d_in[7];
    const float* ew3  = (const float*)d_in[8];
    const float* eb3  = (const float*)d_in[9];
    const float* dw1  = (const float*)d_in[10];
    const float* db1  = (const float*)d_in[11];
    const float* dw2  = (const float*)d_in[12];
    const float* db2  = (const float*)d_in[13];
    const float* dw3  = (const float*)d_in[14];
    const float* db3  = (const float*)d_in[15];

    char* ws = (char*)d_ws;
    double* stats      = (double*)(ws + OFF_STATS);
    int*    bcnt       = (int*)(ws + OFF_BCNT);
    float*  invcnt     = (float*)(ws + OFF_INVCNT);
    float2* agg1       = (float2*)(ws + OFF_AGG1);
    uint*   decw       = (uint*)(ws + OFF_DECW);
    int*    bucket_buf = (int*)(ws + OFF_BUCKET);
    float2* penc       = (float2*)(ws + OFF_PENC);
    int*    pcnt       = (int*)(ws + OFF_PCNT);
    float4* pdec       = (float4*)(ws + OFF_PDEC);
    uint*   encw       = (uint*)(ws + OFF_ENCW);
    float4* out        = (float4*)d_out;

    // zero: stats + bucket counts, contiguous [0, 5120)
    hipMemsetAsync(ws, 0, 5120, stream);

    k_s1<<<S1_BLOCKS, 512, 0, stream>>>(x, stats, ei, bcnt, bucket_buf);
    k_prep<<<1, 256, 0, stream>>>(stats, bn_w, bn_b, ew1, eb1, ew2, eb2, ew3, eb3,
                                  dw1, db1, dw2, db2, dw3, db3, encw, decw);
    k_enc_partial<<<dim3(NB, NSUB), 256, 0, stream>>>(x, bucket_buf, bcnt,
                                                      penc, pcnt, encw);
    k_reduce_enc_p<<<NODE_BLOCKS, 256, 0, stream>>>(penc, pcnt, agg1, invcnt);
    k_dec_partial<<<dim3(NB, NSUB), 256, 0, stream>>>(agg1, bucket_buf, bcnt, pdec, decw);
    k_reduce_dec_p<<<NODE_BLOCKS, 256, 0, stream>>>(pdec, invcnt, out);
}

// Round 12
// 282.611 us; speedup vs baseline: 1.0999x; 1.0245x over previous
//
#include <hip/hip_runtime.h>

#define N_NODES 100000
#define N_EDGES 3200000
#define EPS 1e-5f
#define NODE_BLOCKS 391   // ceil(100000/256)
#define NB 782            // buckets of 128 nodes (dst >> 7)
#define BSTRIDE 4608      // fixed bucket region: mean 4096 + 8 sigma
#define NSUB 3            // chunks of 1536 slots per bucket (3*1536 = 4608)
#define S1_EPB 8192
#define S1_BLOCKS 391

typedef unsigned int uint;
typedef uint u32x4 __attribute__((ext_vector_type(4)));
typedef _Float16 f16x8 __attribute__((ext_vector_type(8)));
typedef float f32x16 __attribute__((ext_vector_type(16)));

static __device__ __forceinline__ f16x8 as_h8(u32x4 u) { return __builtin_bit_cast(f16x8, u); }
static __device__ __forceinline__ uint pkh(float a, float b) {
    return __builtin_bit_cast(uint, __builtin_amdgcn_cvt_pkrtz(a, b));
}
// v_permlane32_swap_b32: a' = [a.lo32 | b.lo32], b' = [a.hi32 | b.hi32]
// volatile + this exact usage is the R1-R3/R7/R8/R10/R11 verified pattern. Do
// NOT touch: R5/R6 experiments around this instruction failed twice.
static __device__ __forceinline__ void swap32(uint& a, uint& b) {
    asm volatile("v_permlane32_swap_b32 %0, %1" : "+v"(a), "+v"(b));
}
// packed f16 relu: max(x, 0) on both halves. rtz-then-relu == relu-then-rtz.
static __device__ __forceinline__ uint prelu(uint u, uint z) {
    uint r;
    asm("v_pk_max_f16 %0, %1, %2" : "=v"(r) : "v"(u), "v"(z));
    return r;
}

#define MFMA(A, B, C) __builtin_amdgcn_mfma_f32_32x32x16_f16(as_h8(A), as_h8(B), (C), 0, 0, 0)

// Repack MFMA C (32 rows x 32 edge-cols, row=(r&3)+8*(r>>2)+4*hi) into the two
// B-fragments for the next K=32 MFMA pair, applying relu in packed f16.
static __device__ __forceinline__ void repack(const f32x16& c, u32x4& f0, u32x4& f1, uint z) {
    uint p0 = prelu(pkh(c[0], c[1]), z),   p1 = prelu(pkh(c[2], c[3]), z);
    uint q0 = prelu(pkh(c[4], c[5]), z),   q1 = prelu(pkh(c[6], c[7]), z);
    uint p2 = prelu(pkh(c[8], c[9]), z),   p3 = prelu(pkh(c[10], c[11]), z);
    uint q2 = prelu(pkh(c[12], c[13]), z), q3 = prelu(pkh(c[14], c[15]), z);
    swap32(p0, q0); swap32(p1, q1);
    swap32(p2, q2); swap32(p3, q3);
    f0.x = p0; f0.y = p1; f0.z = q0; f0.w = q1;
    f1.x = p2; f1.y = p3; f1.z = q2; f1.w = q3;
}

static __device__ __forceinline__ void decode4(const int4& q, int* ss, int* ia) {
    int e0 = q.x, e1 = q.y, e2 = q.z, e3 = q.w;
    ss[0] = e0 & 0x1FFFF; ia[0] = (e0 >> 17) & 127;
    ss[1] = e1 & 0x1FFFF; ia[1] = (e1 >> 17) & 127;
    ss[2] = e2 & 0x1FFFF; ia[2] = (e2 >> 17) & 127;
    ss[3] = e3 & 0x1FFFF; ia[3] = (e3 >> 17) & 127;
    #pragma unroll
    for (int k = 0; k < 4; k++)
        if (ss[k] >= N_NODES) ss[k] = 0;   // slots >= cb hold stale garbage
}

// ---- workspace layout (bytes) ----
#define OFF_STATS  0          // 8 doubles (bn sums)          [zeroed]
#define OFF_BCNT   1024       // int[782] bucket counts       [zeroed]
#define OFF_INVCNT 5120       // float[100000]
#define OFF_AGG1   405120     // float2[100000]
#define OFF_DECW   1205120    // dec MFMA tables: 2112 dwords = 8448B
#define OFF_BUCKET 1214848    // int[782*4608] packed entries s|(dloc<<17) (14.4 MB)
#define OFF_PENC   15629696   // float2[782*3*128] enc partials (2.4 MB)
#define OFF_PCNT   22836608   // int[782*3*128]   count partials (1.2 MB)
#define OFF_PDEC   26440064   // float4[782*3*128] dec partials (4.8 MB)
#define OFF_ENCW   26440064   // enc tables alias pdec head (dead before k_dec writes)

// table layout (dword offsets), identical enc/dec:
//   [0,256)      W1 hi (+bias row: enc k=8, dec k=4)
//   [256,512)    W1 lo (+bias residual row)
//   [512,768)    W2 hi k-tile0   [768,1024)  W2 hi k-tile1
//   [1024,1280)  W2 lo k-tile0   [1280,1536) W2 lo k-tile1
//   [1536,1792)  W3 k-tile0      [1792,2048) W3 k-tile1  (hi only; rows remapped)
//   [2048,2080)  b2 C-frag tab (f32, [hi*16+r])
//   [2080,2112)  b3 tab (remapped rows)

// hi/lo f16 split: part 0 = f16(v), part 1 = f16(v - f16(v)); packs a pair.
static __device__ __forceinline__ uint pk_part(float a, float b, int part) {
    _Float16 ah = (_Float16)a, bh = (_Float16)b;
    if (part) {
        a -= (float)ah; b -= (float)bh;
        ah = (_Float16)a; bh = (_Float16)b;
    }
    return (uint)__builtin_bit_cast(unsigned short, ah) |
           ((uint)__builtin_bit_cast(unsigned short, bh) << 16);
}

// Build all MFMA fragment tables (R8/R10-verified). A[m][k]: m=lane&31, k=8*hi+e.
// L1 bias rides a weight ROW: enc A[m][8]=BN-folded b1, dec A[m][4]=db1.
// W3 rows remapped for split atomics; W3 hi-part only.
__global__ __launch_bounds__(256) void k_prep(const double* __restrict__ stats,
                                              const float* __restrict__ bn_w,
                                              const float* __restrict__ bn_b,
                                              const float* __restrict__ ew1,
                                              const float* __restrict__ eb1,
                                              const float* __restrict__ ew2,
                                              const float* __restrict__ eb2,
                                              const float* __restrict__ ew3,
                                              const float* __restrict__ eb3,
                                              const float* __restrict__ dw1,
                                              const float* __restrict__ db1,
                                              const float* __restrict__ dw2,
                                              const float* __restrict__ db2,
                                              const float* __restrict__ dw3,
                                              const float* __restrict__ db3,
                                              uint* __restrict__ encw,
                                              uint* __restrict__ decw) {
    int t = threadIdx.x;
    int lane = t >> 2, d = t & 3;
    int hi = lane >> 5, m = lane & 31;

    const double inv_n = 1.0 / (double)N_NODES;
    float sc[4], sh[4];
    #pragma unroll
    for (int dd = 0; dd < 4; dd++) {
        double mu = stats[dd] * inv_n;
        double vr = stats[4 + dd] * inv_n - mu * mu;
        float rs = (float)(1.0 / sqrt(vr + (double)EPS));
        sc[dd] = rs * bn_w[dd];
        sh[dd] = bn_b[dd] - (float)mu * sc[dd];
    }
    float b1p = eb1[m];
    #pragma unroll
    for (int dd = 0; dd < 4; dd++) b1p += ew1[dd * 32 + m] * sh[dd];

    int k0 = 8 * hi + 2 * d;
    {   // enc W1 hi+lo (BN-folded weights) + bias row k=8
        float v0 = (k0 < 8) ? ew1[k0 * 32 + m] * sc[k0 & 3]
                            : (k0 == 8 ? b1p : 0.f);
        float v1 = (k0 + 1 < 8) ? ew1[(k0 + 1) * 32 + m] * sc[(k0 + 1) & 3] : 0.f;
        encw[t] = pk_part(v0, v1, 0);
        encw[256 + t] = pk_part(v0, v1, 1);
    }
    {   // dec W1 hi+lo + bias row k=4
        float v0 = (k0 < 4) ? dw1[k0 * 32 + m] : (k0 == 4 ? db1[m] : 0.f);
        float v1 = (k0 + 1 < 4) ? dw1[(k0 + 1) * 32 + m] : 0.f;
        decw[t] = pk_part(v0, v1, 0);
        decw[256 + t] = pk_part(v0, v1, 1);
    }
    #pragma unroll
    for (int tile = 0; tile < 2; tile++) {   // W2 (K=32, 2 k-tiles), hi+lo
        int k = 16 * tile + k0;
        {
            float a = ew2[k * 32 + m], bb = ew2[(k + 1) * 32 + m];
            encw[512 + tile * 256 + t] = pk_part(a, bb, 0);
            encw[1024 + tile * 256 + t] = pk_part(a, bb, 1);
        }
        {
            float a = dw2[k * 32 + m], bb = dw2[(k + 1) * 32 + m];
            decw[512 + tile * 256 + t] = pk_part(a, bb, 0);
            decw[1024 + tile * 256 + t] = pk_part(a, bb, 1);
        }
        {   // enc W3 (32->2), hi only, rows {0,4}
            float a = 0.f, bb = 0.f;
            if (m == 0 || m == 4) {
                int o = m >> 2;
                a = ew3[k * 2 + o]; bb = ew3[(k + 1) * 2 + o];
            }
            encw[1536 + tile * 256 + t] = pk_part(a, bb, 0);
        }
        {   // dec W3 (32->4), hi only, rows {0,1,4,5}
            float a = 0.f, bb = 0.f;
            if ((m & 3) < 2 && m < 6) {
                int o = (m & 1) + 2 * (m >> 2);
                a = dw3[k * 4 + o]; bb = dw3[(k + 1) * 4 + o];
            }
            decw[1536 + tile * 256 + t] = pk_part(a, bb, 0);
        }
    }
    if (t < 32) {   // bias tabs: index hh*16+r, value bias[row(r,hh)]
        int hh = t >> 4, r = t & 15;
        int row = (r & 3) + 8 * (r >> 2) + 4 * hh;
        ((float*)encw)[2048 + t] = eb2[row];
        ((float*)encw)[2080 + t] = (row == 0) ? eb3[0] : (row == 4) ? eb3[1] : 0.f;
        ((float*)decw)[2048 + t] = db2[row];
        ((float*)decw)[2080 + t] =
            ((row & 3) < 2 && row < 6) ? db3[(row & 1) + 2 * (row >> 2)] : 0.f;
    }
}

// S1 + fused BN stats, 512 threads (R11-verified).
__global__ __launch_bounds__(512) void k_s1(const float* __restrict__ x,
                                            double* __restrict__ stats,
                                            const int* __restrict__ ei,
                                            int* __restrict__ bcnt,
                                            int* __restrict__ bucket_buf) {
    __shared__ int hist[NB];
    __shared__ int base[NB];
    __shared__ int run[NB];
    __shared__ int gbase[NB];
    __shared__ int entries[S1_EPB];
    __shared__ unsigned short bk16[S1_EPB];
    __shared__ int wsum[8];
    __shared__ double smem_bn[8][8];
    int tid = threadIdx.x;

    {   // ---- BN stats slice ----
        int i = blockIdx.x * 512 + tid;
        float4 v = make_float4(0.f, 0.f, 0.f, 0.f);
        if (i < N_NODES) v = ((const float4*)x)[i];
        double a[8];
        a[0] = v.x; a[1] = v.y; a[2] = v.z; a[3] = v.w;
        a[4] = (double)v.x * v.x; a[5] = (double)v.y * v.y;
        a[6] = (double)v.z * v.z; a[7] = (double)v.w * v.w;
        #pragma unroll
        for (int off = 32; off > 0; off >>= 1) {
            #pragma unroll
            for (int j = 0; j < 8; j++) a[j] += __shfl_down(a[j], off);
        }
        int wave = tid >> 6, lane = tid & 63;
        if (lane == 0) {
            #pragma unroll
            for (int j = 0; j < 8; j++) smem_bn[wave][j] = a[j];
        }
        __syncthreads();
        if (tid == 0) {
            #pragma unroll
            for (int j = 0; j < 8; j++) {
                double t2 = 0.0;
                #pragma unroll
                for (int w = 0; w < 8; w++) t2 += smem_bn[w][j];
                atomicAdd(&stats[j], t2);
            }
        }
    }

    // ---- edge binning ----
    int e0 = blockIdx.x * S1_EPB;
    for (int i = tid; i < NB; i += 512) hist[i] = 0;
    __syncthreads();
    #pragma unroll
    for (int k = 0; k < S1_EPB / 512; k++) {
        int e = e0 + k * 512 + tid;
        if (e < N_EDGES) atomicAdd(&hist[ei[N_EDGES + e] >> 7], 1);
    }
    __syncthreads();
    int t4 = tid * 4;
    int h0 = (t4 + 0 < NB) ? hist[t4 + 0] : 0;
    int h1 = (t4 + 1 < NB) ? hist[t4 + 1] : 0;
    int h2 = (t4 + 2 < NB) ? hist[t4 + 2] : 0;
    int h3 = (t4 + 3 < NB) ? hist[t4 + 3] : 0;
    int tsum = h0 + h1 + h2 + h3;
    int lane = tid & 63, wv = tid >> 6;
    int xs = tsum;
    #pragma unroll
    for (int off = 1; off < 64; off <<= 1) {
        int u = __shfl_up(xs, off);
        if (lane >= off) xs += u;
    }
    if (lane == 63) wsum[wv] = xs;
    __syncthreads();
    int wo = 0;
    #pragma unroll
    for (int w = 0; w < 8; w++) if (w < wv) wo += wsum[w];
    int texcl = wo + xs - tsum;
    if (t4 + 0 < NB) base[t4 + 0] = texcl;
    if (t4 + 1 < NB) base[t4 + 1] = texcl + h0;
    if (t4 + 2 < NB) base[t4 + 2] = texcl + h0 + h1;
    if (t4 + 3 < NB) base[t4 + 3] = texcl + h0 + h1 + h2;
    __syncthreads();
    for (int i = tid; i < NB; i += 512) {
        int h = hist[i];
        gbase[i] = i * BSTRIDE + (h ? atomicAdd(&bcnt[i], h) : 0);
        run[i] = base[i];
    }
    __syncthreads();
    #pragma unroll
    for (int k = 0; k < S1_EPB / 512; k++) {
        int e = e0 + k * 512 + tid;
        if (e < N_EDGES) {
            int s = ei[e];
            int d = ei[N_EDGES + e];
            int b = d >> 7;
            int r = atomicAdd(&run[b], 1);   // LDS
            entries[r] = s | ((d & 127) << 17);
            bk16[r] = (unsigned short)b;
        }
    }
    __syncthreads();
    int nloc = min(S1_EPB, N_EDGES - e0);
    for (int idx = tid; idx < nloc; idx += 512) {
        int b = bk16[idx];
        bucket_buf[gbase[b] + (idx - base[b])] = entries[idx];
    }
}

// Fused (BN-folded) encoder 8->32->32->2, all three layers on the matrix pipe.
// R12: de-correlated quad assignment Q = sub*384 + (wv+4w) + 12*col
// (bijective over the sub-region; wv+4w covers residues 0..11). A tile's 32
// lanes are 48 slots (~1.5 dst nodes) apart -> ~30 distinct LDS-atomic
// addresses instead of ~4 (8-way same-address RMW serialization was the
// pre-session-R17-measured cost silently dropped in R2's MFMA rewrite).
// Tile arithmetic unchanged (R8/R10/R11-verified).
__global__ __launch_bounds__(256, 4) void k_enc_partial(const float* __restrict__ x,
                                                        const int* __restrict__ bucket_buf,
                                                        const int* __restrict__ bcnt,
                                                        float2* __restrict__ penc,
                                                        int* __restrict__ pcnt,
                                                        const uint* __restrict__ encw) {
    __shared__ float4 xs[128];
    __shared__ float acc0[128], acc1[128];
    __shared__ int lc[128];
    int b = blockIdx.x, sub = blockIdx.y, tid = threadIdx.x;
    int lane = tid & 63, hi = lane >> 5, col = lane & 31, wv = tid >> 6;
    int cb = bcnt[b];
    int node0 = b << 7;

    if (tid < 128) {
        acc0[tid] = 0.f; acc1[tid] = 0.f; lc[tid] = 0;
        int n = node0 + tid;
        if (n >= N_NODES) n = 0;
        xs[tid] = ((const float4*)x)[n];   // raw x (BN folded into weights)
    }
    __syncthreads();

    const u32x4* W4 = (const u32x4*)encw;
    u32x4 w1h  = W4[lane],       w1l  = W4[64 + lane];
    u32x4 w2h0 = W4[128 + lane], w2h1 = W4[192 + lane];
    u32x4 w2l0 = W4[256 + lane], w2l1 = W4[320 + lane];
    u32x4 w30  = W4[384 + lane], w31  = W4[448 + lane];
    const float* tf = (const float*)encw;
    f32x16 b2f;
    {
        const float4* p2 = (const float4*)(tf + 2048 + hi * 16);
        #pragma unroll
        for (int q = 0; q < 4; q++) {
            float4 c = p2[q];
            b2f[4 * q] = c.x; b2f[4 * q + 1] = c.y; b2f[4 * q + 2] = c.z; b2f[4 * q + 3] = c.w;
        }
    }
    float bc0 = tf[2080 + hi * 16] - b2f[0];
    float* accH = hi ? acc1 : acc0;
    uint z = 0;

    int qbase = sub * 384 + wv;          // quad units; windows at +4, +8
    if (4 * qbase < cb) {
        const int4* BB = (const int4*)&bucket_buf[b * BSTRIDE];
        int q0 = qbase + 12 * col;       // this lane's window-0 quad
        int4 qa = BB[q0];
        int4 qb = BB[q0 + 4];
        int4 qc = BB[q0 + 8];
        bool act1 = 4 * (qbase + 4) < cb;
        bool act2 = 4 * (qbase + 8) < cb;

        // slot0 = 4*quad for this lane's window; gate per tile: (slot0+j) < cb
        auto enc_win = [&](const int* ia, const float4* xg, int slot0) {
            #pragma unroll
            for (int j = 0; j < 4; j++) {
                u32x4 xf;
                if (hi == 0) {
                    float4 xi = xs[ia[j]];
                    xf.x = pkh(xi.x, xi.y);
                    xf.y = pkh(xi.z, xi.w);
                    xf.z = pkh(xg[j].x - xi.x, xg[j].y - xi.y);
                    xf.w = pkh(xg[j].z - xi.z, xg[j].w - xi.w);
                } else {
                    xf.x = 0x00003C00u;   // k=8 bias row == 1.0
                    xf.y = 0u; xf.z = 0u; xf.w = 0u;
                }
                f32x16 c = {};
                c = MFMA(w1h, xf, c);
                c = MFMA(w1l, xf, c);
                u32x4 f0, f1;
                repack(c, f0, f1, z);
                f32x16 c2 = MFMA(w2h0, f0, b2f);
                c2 = MFMA(w2h1, f1, c2);
                c2 = MFMA(w2l0, f0, c2);
                c2 = MFMA(w2l1, f1, c2);
                u32x4 e0, e1;
                repack(c2, e0, e1, z);
                f32x16 c3 = MFMA(w30, e0, b2f);   // init garbage cancelled by bc0
                c3 = MFMA(w31, e1, c3);
                float o = fmaxf(c3[0] + bc0, 0.f);
                if ((slot0 + j) < cb) {
                    atomicAdd(&accH[ia[j]], o);
                    if (hi == 0) atomicAdd(&lc[ia[j]], 1);
                }
            }
        };

        int s0[4], s1[4], s2[4], ia0[4], ia1[4], ia2[4];
        float4 xg0[4], xg1[4], xg2[4];
        decode4(qa, s0, ia0);
        if (hi == 0) {
            #pragma unroll
            for (int k = 0; k < 4; k++) xg0[k] = ((const float4*)x)[s0[k]];
        }
        if (act1) {
            decode4(qb, s1, ia1);
            if (hi == 0) {
                #pragma unroll
                for (int k = 0; k < 4; k++) xg1[k] = ((const float4*)x)[s1[k]];
            }
        }
        enc_win(ia0, xg0, 4 * q0);
        if (act2) {
            decode4(qc, s2, ia2);
            if (hi == 0) {
                #pragma unroll
                for (int k = 0; k < 4; k++) xg2[k] = ((const float4*)x)[s2[k]];
            }
        }
        if (act1) enc_win(ia1, xg1, 4 * (q0 + 4));
        if (act2) enc_win(ia2, xg2, 4 * (q0 + 8));
    }
    __syncthreads();
    if (tid < 128) {
        int pb = b * NSUB + sub;
        penc[pb * 128 + tid] = make_float2(acc0[tid], acc1[tid]);
        pcnt[pb * 128 + tid] = lc[tid];
    }
}

// sum NSUB chunk-partials per node -> agg1 (mean) + invcnt
__global__ __launch_bounds__(256) void k_reduce_enc_p(const float2* __restrict__ penc,
                                                      const int* __restrict__ pcnt,
                                                      float2* __restrict__ agg1,
                                                      float* __restrict__ invcnt) {
    int i = blockIdx.x * 256 + threadIdx.x;
    if (i >= N_NODES) return;
    int b = i >> 7, l = i & 127;
    float a0 = 0.f, a1 = 0.f;
    int c = 0;
    #pragma unroll
    for (int sub = 0; sub < NSUB; sub++) {
        int idx = (b * NSUB + sub) * 128 + l;
        float2 p = penc[idx];
        a0 += p.x; a1 += p.y;
        c += pcnt[idx];
    }
    float ic = 1.0f / (float)(c > 1 ? c : 1);
    invcnt[i] = ic;
    agg1[i] = make_float2(a0 * ic, a1 * ic);
}

// Fused decoder 4->32->32->4, same de-correlated quad assignment.
// Split atomics: hi=0 -> out0,1; hi=1 -> out2,3 (W3 rows 0,1,4,5).
__global__ __launch_bounds__(256, 4) void k_dec_partial(const float2* __restrict__ henc,
                                                        const int* __restrict__ bucket_buf,
                                                        const int* __restrict__ bcnt,
                                                        float4* __restrict__ pdec,
                                                        const uint* __restrict__ decw) {
    __shared__ float2 hld[128];
    __shared__ float a0s[128], a1s[128], a2s[128], a3s[128];
    int b = blockIdx.x, sub = blockIdx.y, tid = threadIdx.x;
    int lane = tid & 63, hi = lane >> 5, col = lane & 31, wv = tid >> 6;
    int cb = bcnt[b];
    int node0 = b << 7;

    if (tid < 128) {
        a0s[tid] = 0.f; a1s[tid] = 0.f; a2s[tid] = 0.f; a3s[tid] = 0.f;
        int n = node0 + tid;
        if (n >= N_NODES) n = 0;
        hld[tid] = henc[n];
    }
    __syncthreads();

    const u32x4* W4 = (const u32x4*)decw;
    u32x4 w1h  = W4[lane],       w1l  = W4[64 + lane];
    u32x4 v2h0 = W4[128 + lane], v2h1 = W4[192 + lane];
    u32x4 v2l0 = W4[256 + lane], v2l1 = W4[320 + lane];
    u32x4 w30  = W4[384 + lane], w31  = W4[448 + lane];
    const float* tf = (const float*)decw;
    f32x16 b2f;
    {
        const float4* p2 = (const float4*)(tf + 2048 + hi * 16);
        #pragma unroll
        for (int q = 0; q < 4; q++) {
            float4 c = p2[q];
            b2f[4 * q] = c.x; b2f[4 * q + 1] = c.y; b2f[4 * q + 2] = c.z; b2f[4 * q + 3] = c.w;
        }
    }
    float bc0 = tf[2080 + hi * 16 + 0] - b2f[0];
    float bc1 = tf[2080 + hi * 16 + 1] - b2f[1];
    float* accA = hi ? a2s : a0s;
    float* accB = hi ? a3s : a1s;
    uint z = 0;

    int qbase = sub * 384 + wv;
    if (4 * qbase < cb) {
        const int4* BB = (const int4*)&bucket_buf[b * BSTRIDE];
        int q0 = qbase + 12 * col;
        int4 qa = BB[q0];
        int4 qb = BB[q0 + 4];
        int4 qc = BB[q0 + 8];
        bool act1 = 4 * (qbase + 4) < cb;
        bool act2 = 4 * (qbase + 8) < cb;

        auto dec_win = [&](const int* ia, const float2* hj, int slot0) {
            #pragma unroll
            for (int j = 0; j < 4; j++) {
                u32x4 xf;
                if (hi == 0) {
                    float2 h2 = hld[ia[j]];
                    xf.x = pkh(h2.x, h2.y);
                    xf.y = pkh(hj[j].x - h2.x, hj[j].y - h2.y);
                    xf.z = 0x00003C00u;   // k=4 bias row == 1.0
                    xf.w = 0u;
                } else {
                    xf.x = 0u; xf.y = 0u; xf.z = 0u; xf.w = 0u;
                }
                f32x16 c = {};
                c = MFMA(w1h, xf, c);
                c = MFMA(w1l, xf, c);
                u32x4 f0, f1;
                repack(c, f0, f1, z);
                f32x16 c2 = MFMA(v2h0, f0, b2f);
                c2 = MFMA(v2h1, f1, c2);
                c2 = MFMA(v2l0, f0, c2);
                c2 = MFMA(v2l1, f1, c2);
                u32x4 e0, e1;
                repack(c2, e0, e1, z);
                f32x16 c3 = MFMA(w30, e0, b2f);
                c3 = MFMA(w31, e1, c3);
                float o0 = c3[0] + bc0;
                float o1 = c3[1] + bc1;
                if ((slot0 + j) < cb) {
                    atomicAdd(&accA[ia[j]], o0);
                    atomicAdd(&accB[ia[j]], o1);
                }
            }
        };

        int s0[4], s1[4], s2[4], ia0[4], ia1[4], ia2[4];
        float2 hg0[4], hg1[4], hg2[4];
        decode4(qa, s0, ia0);
        if (hi == 0) {
            #pragma unroll
            for (int k = 0; k < 4; k++) hg0[k] = henc[s0[k]];
        }
        if (act1) {
            decode4(qb, s1, ia1);
            if (hi == 0) {
                #pragma unroll
                for (int k = 0; k < 4; k++) hg1[k] = henc[s1[k]];
            }
        }
        dec_win(ia0, hg0, 4 * q0);
        if (act2) {
            decode4(qc, s2, ia2);
            if (hi == 0) {
                #pragma unroll
                for (int k = 0; k < 4; k++) hg2[k] = henc[s2[k]];
            }
        }
        if (act1) dec_win(ia1, hg1, 4 * (q0 + 4));
        if (act2) dec_win(ia2, hg2, 4 * (q0 + 8));
    }
    __syncthreads();
    if (tid < 128) {
        int pb = b * NSUB + sub;
        pdec[pb * 128 + tid] = make_float4(a0s[tid], a1s[tid], a2s[tid], a3s[tid]);
    }
}

// sum NSUB chunk-partials per node -> final output (mean)
__global__ __launch_bounds__(256) void k_reduce_dec_p(const float4* __restrict__ pdec,
                                                      const float* __restrict__ invcnt,
                                                      float4* __restrict__ out) {
    int i = blockIdx.x * 256 + threadIdx.x;
    if (i >= N_NODES) return;
    int b = i >> 7, l = i & 127;
    float a0 = 0.f, a1 = 0.f, a2 = 0.f, a3 = 0.f;
    #pragma unroll
    for (int sub = 0; sub < NSUB; sub++) {
        float4 p = pdec[(b * NSUB + sub) * 128 + l];
        a0 += p.x; a1 += p.y; a2 += p.z; a3 += p.w;
    }
    float ic = invcnt[i];
    out[i] = make_float4(a0 * ic, a1 * ic, a2 * ic, a3 * ic);
}

extern "C" void kernel_launch(void* const* d_in, const int* in_sizes, int n_in,
                              void* d_out, int out_size, void* d_ws, size_t ws_size,
                              hipStream_t stream) {
    const float* x    = (const float*)d_in[0];
    const int*   ei   = (const int*)d_in[1];
    const float* bn_w = (const float*)d_in[2];
    const float* bn_b = (const float*)d_in[3];
    const float* ew1  = (const float*)d_in[4];
    const float* eb1  = (const float*)d_in[5];
    const float* ew2  = (const float*)d_in[6];
    const float* eb2  = (const float*)d_in[7];
    const float* ew3  = (const float*)d_in[8];
    const float* eb3  = (const float*)d_in[9];
    const float* dw1  = (const float*)d_in[10];
    const float* db1  = (const float*)d_in[11];
    const float* dw2  = (const float*)d_in[12];
    const float* db2  = (const float*)d_in[13];
    const float* dw3  = (const float*)d_in[14];
    const float* db3  = (const float*)d_in[15];

    char* ws = (char*)d_ws;
    double* stats      = (double*)(ws + OFF_STATS);
    int*    bcnt       = (int*)(ws + OFF_BCNT);
    float*  invcnt     = (float*)(ws + OFF_INVCNT);
    float2* agg1       = (float2*)(ws + OFF_AGG1);
    uint*   decw       = (uint*)(ws + OFF_DECW);
    int*    bucket_buf = (int*)(ws + OFF_BUCKET);
    float2* penc       = (float2*)(ws + OFF_PENC);
    int*    pcnt       = (int*)(ws + OFF_PCNT);
    float4* pdec       = (float4*)(ws + OFF_PDEC);
    uint*   encw       = (uint*)(ws + OFF_ENCW);
    float4* out        = (float4*)d_out;

    // zero: stats + bucket counts, contiguous [0, 5120)
    hipMemsetAsync(ws, 0, 5120, stream);

    k_s1<<<S1_BLOCKS, 512, 0, stream>>>(x, stats, ei, bcnt, bucket_buf);
    k_prep<<<1, 256, 0, stream>>>(stats, bn_w, bn_b, ew1, eb1, ew2, eb2, ew3, eb3,
                                  dw1, db1, dw2, db2, dw3, db3, encw, decw);
    k_enc_partial<<<dim3(NB, NSUB), 256, 0, stream>>>(x, bucket_buf, bcnt,
                                                      penc, pcnt, encw);
    k_reduce_enc_p<<<NODE_BLOCKS, 256, 0, stream>>>(penc, pcnt, agg1, invcnt);
    k_dec_partial<<<dim3(NB, NSUB), 256, 0, stream>>>(agg1, bucket_buf, bcnt, pdec, decw);
    k_reduce_dec_p<<<NODE_BLOCKS, 256, 0, stream>>>(pdec, invcnt, out);
}